// Round 4
// baseline (384.146 us; speedup 1.0000x reference)
//
#include <hip/hip_runtime.h>
#include <cstdint>
#include <cstddef>

// ---------------- problem constants ----------------
#define TOKENS   65536      // B*N = 16*4096
#define KDIM     256        // model dim
#define HIDDEN   1024       // 4*dim
#define BM       128        // tokens per block
#define HC       32         // hidden chunk width
#define NCHUNK   32         // HIDDEN / HC
#define NTHREADS 512        // 8 waves
#define NBLOCKS  (TOKENS / BM)

// LDS map (160 KB dynamic, exactly the CU's LDS):
//   W1buf[2] @0      : each 32K = W1h 16K | W1l 16K      (64 KB)
//   W2buf[2] @65536  : each 32K = W2h 16K | W2l 16K      (64 KB)
//   G[2]     @131072 : each 16K = u32-packed (gh|gl<<16) [128][32]
//   P0 overlay: x_hi @0..64K, x_lo @64K..128K (pre-loop only)
//   epilogue:  h fp16 @0..64K ; hstg f32[128][16] @65536
#define W2OFF 65536
#define GOFF  131072
#define LDS_BYTES 163840

using f16x8 = __attribute__((ext_vector_type(8))) _Float16;
using f16x4 = __attribute__((ext_vector_type(4))) _Float16;
using f32x4 = __attribute__((ext_vector_type(4))) float;
using u32x4 = __attribute__((ext_vector_type(4))) uint32_t;

// fp16 hi/lo split weights, pre-transposed + pre-swizzled per chunk so a
// LINEAR global_load_lds stage produces the swizzled LDS image directly.
// W1 plane: [c][n=32][k=256], byte = n*512 + ((g*16) ^ ((n&7)<<4))
// W2 plane: [c][n=256][k=32], byte = n*64  + ((g*16) ^ (((n>>1)&3)<<4))
__device__ __align__(16) _Float16 g_W1h[NCHUNK * HC * KDIM];
__device__ __align__(16) _Float16 g_W1l[NCHUNK * HC * KDIM];
__device__ __align__(16) _Float16 g_W2h[NCHUNK * KDIM * HC];
__device__ __align__(16) _Float16 g_W2l[NCHUNK * KDIM * HC];
__device__ __align__(16) _Float16 g_Whh[16 * KDIM];            // head rows j(16) x k(256)
__device__ __align__(16) _Float16 g_Whl[16 * KDIM];

// ---------------- prep: split + transpose + swizzle (dest-coalesced) ----------------
__global__ __launch_bounds__(256) void prep_kernel(
    const float* __restrict__ W1, const float* __restrict__ W2,
    const float* __restrict__ Wval, const float* __restrict__ Wvec) {
  const int tid = blockIdx.x * 256 + threadIdx.x;
  if (tid < 32768) {
    // W1: c(32) x n(32) x gd(32 dest k-octets)
    const int c = tid >> 10, n = (tid >> 5) & 31, gd = tid & 31;
    const int g = gd ^ (n & 7);          // swizzle is involutive on octet index
    const int hid = c * 32 + n;
    f16x8 hv, lv;
#pragma unroll
    for (int j = 0; j < 8; ++j) {
      const float wv = W1[(g * 8 + j) * HIDDEN + hid];
      const _Float16 hi = (_Float16)wv;
      hv[j] = hi;
      lv[j] = (_Float16)(wv - (float)hi);
    }
    const int dst = c * 8192 + n * 256 + gd * 8;
    *(f16x8*)(g_W1h + dst) = hv;
    *(f16x8*)(g_W1l + dst) = lv;
  } else if (tid < 65536) {
    // W2: c(32) x n(256) x gd(4)
    const int t = tid - 32768;
    const int c = t >> 10, n = (t >> 2) & 255, gd = t & 3;
    const int g = gd ^ ((n >> 1) & 3);
    f16x8 hv, lv;
#pragma unroll
    for (int j = 0; j < 8; ++j) {
      const float wv = W2[(c * 32 + g * 8 + j) * KDIM + n];
      const _Float16 hi = (_Float16)wv;
      hv[j] = hi;
      lv[j] = (_Float16)(wv - (float)hi);
    }
    const int dst = c * 8192 + n * 32 + gd * 8;
    *(f16x8*)(g_W2h + dst) = hv;
    *(f16x8*)(g_W2l + dst) = lv;
  } else if (tid < 65536 + 4096) {
    const int e = tid - 65536;
    const int j16 = e >> 8, k = e & 255;
    float wv = 0.f;
    if (j16 < 3) wv = Wval[k * 3 + j16];
    else if (j16 < 12) wv = Wvec[k * 9 + (j16 - 3)];
    const _Float16 hi = (_Float16)wv;
    g_Whh[e] = hi;
    g_Whl[e] = (_Float16)(wv - (float)hi);
  }
}

// stage one 32KB W-pair (h+l planes): 8 waves x 4KB = 4x 1KB loads per wave.
// EXACTLY 4 VMEM ops per wave -> vmcnt ledger stays exact.
__device__ __forceinline__ void stage_W1(char* smem, int par, int c, int w, int lane) {
  const char* base = (w < 4) ? (const char*)g_W1h : (const char*)g_W1l;
  const char* s = base + (size_t)c * 16384 + (size_t)(w & 3) * 4096 + (size_t)lane * 16;
  char* d = smem + par * 32768 + ((w < 4) ? 0 : 16384) + (w & 3) * 4096;
#pragma unroll
  for (int i = 0; i < 4; ++i) {
    __builtin_amdgcn_global_load_lds(
        (__attribute__((address_space(1))) void*)(void*)(s + i * 1024),
        (__attribute__((address_space(3))) void*)(d + i * 1024), 16, 0, 0);
  }
}
__device__ __forceinline__ void stage_W2(char* smem, int par, int c, int w, int lane) {
  const char* base = (w < 4) ? (const char*)g_W2h : (const char*)g_W2l;
  const char* s = base + (size_t)c * 16384 + (size_t)(w & 3) * 4096 + (size_t)lane * 16;
  char* d = smem + W2OFF + par * 32768 + ((w < 4) ? 0 : 16384) + (w & 3) * 4096;
#pragma unroll
  for (int i = 0; i < 4; ++i) {
    __builtin_amdgcn_global_load_lds(
        (__attribute__((address_space(1))) void*)(void*)(s + i * 1024),
        (__attribute__((address_space(3))) void*)(d + i * 1024), 16, 0, 0);
  }
}

__device__ __forceinline__ f16x8 unpack_half(const u32x4 a, const u32x4 b, uint32_t sel) {
  u32x4 r;
  r[0] = __builtin_amdgcn_perm(a[1], a[0], sel);
  r[1] = __builtin_amdgcn_perm(a[3], a[2], sel);
  r[2] = __builtin_amdgcn_perm(b[1], b[0], sel);
  r[3] = __builtin_amdgcn_perm(b[3], b[2], sel);
  return __builtin_bit_cast(f16x8, r);
}

#define MFMA16(a, b, c) __builtin_amdgcn_mfma_f32_16x16x32_f16((a), (b), (c), 0, 0, 0)

// One chunk iteration. PAR = t&1 (compile-time). DO_G2: GEMM2 of chunk t-1.
// Runtime guard (T<32) disables GEMM1/GELU/stage on the final drain iteration.
//
// Sync contract (fixes R3's cross-wave race):
//   entry: ALL waves' W1(T)/W2(T-1) DMAs certified landed (barrier B of T-1).
//   body reads freely; barrier A = reads done + G[PAR] visible;
//   stage into freed bufs; vmcnt(8) certifies MY W1(T+1)/W2(T) landed;
//   barrier B publishes that certification to all waves.
template <int PAR, bool DO_G2>
__device__ __forceinline__ void chunk_body(
    int T, char* __restrict__ smem,
    const f16x8 (&xah)[2][8], const f16x8 (&xal)[2][8],
    f32x4 (&acc2)[2][8], float& b_cur, const float* __restrict__ b1g,
    int wm, int wn, int l15, int lg, int w, int lane) {
  const f32x4 z4 = {0.f, 0.f, 0.f, 0.f};

  float b_nxt = 0.f;
  if (T < 32) {
    int idx = (T + 1) * 32 + wn * 16 + l15;
    idx = idx > 1023 ? 1023 : idx;       // T=31 loads a clamped dummy (unused)
    b_nxt = b1g[idx];                    // 1 VMEM op, accounted in the ledger
  }

  // ---- GEMM1(T): accA = xh*W1h ; accB = xh*W1l + xl*W1h (chained) ----
  f32x4 accA[2] = {z4, z4}, accB[2] = {z4, z4};
  if (T < 32) {
    const int n = wn * 16 + l15;
    const uint32_t nbase = (uint32_t)(n * 512);
    const uint32_t nswz  = (uint32_t)((n & 7) << 4);
    const char* w1b = smem + PAR * 32768;
#pragma unroll
    for (int ks = 0; ks < 8; ++ks) {
      const uint32_t off = nbase + (((uint32_t)(ks * 64 + lg * 16)) ^ nswz);
      const f16x8 bh = *(const f16x8*)(w1b + off);
      const f16x8 bl = *(const f16x8*)(w1b + 16384 + off);
#pragma unroll
      for (int mt = 0; mt < 2; ++mt) {
        accA[mt] = MFMA16(xah[mt][ks], bh, accA[mt]);
        accB[mt] = MFMA16(xah[mt][ks], bl, accB[mt]);
        accB[mt] = MFMA16(xal[mt][ks], bh, accB[mt]);
      }
    }
  }

  // ---- GEMM2(T-1): acc2 += gh*W2h + gh*W2l + gl*W2h (prev chunk's G) ----
  if (DO_G2) {
    const char* w2b = smem + W2OFF + (PAR ^ 1) * 32768;
    const char* gb  = smem + GOFF + (PAR ^ 1) * 16384;
    f16x8 ah[2], al[2];
#pragma unroll
    for (int mt = 0; mt < 2; ++mt) {
      const int row = wm * 32 + mt * 16 + l15;
      const uint32_t sw = (uint32_t)((row & 7) << 4);
      const uint32_t base = (uint32_t)(row * 128);
      const u32x4 w0 = *(const u32x4*)(gb + base + (((uint32_t)(lg * 32)) ^ sw));
      const u32x4 w1v = *(const u32x4*)(gb + base + (((uint32_t)(lg * 32 + 16)) ^ sw));
      ah[mt] = unpack_half(w0, w1v, 0x05040100u);   // gh lanes
      al[mt] = unpack_half(w0, w1v, 0x07060302u);   // gl lanes
    }
#pragma unroll
    for (int nt = 0; nt < 8; ++nt) {
      const int n = wn * 128 + nt * 16 + l15;
      const uint32_t off = (uint32_t)(n * 64) +
                           (((uint32_t)(lg * 16)) ^ (((n >> 1) & 3) << 4));
      const f16x8 bh = *(const f16x8*)(w2b + off);
      const f16x8 bl = *(const f16x8*)(w2b + 16384 + off);
#pragma unroll
      for (int mt = 0; mt < 2; ++mt) {
        acc2[mt][nt] = MFMA16(ah[mt], bh, acc2[mt][nt]);
        acc2[mt][nt] = MFMA16(ah[mt], bl, acc2[mt][nt]);
        acc2[mt][nt] = MFMA16(al[mt], bh, acc2[mt][nt]);
      }
    }
  }

  // ---- GELU(T): v*sigmoid(2u) form (no full divide), fp16 split, write G[PAR] ----
  if (T < 32) {
    constexpr float C2 = -1.5957691216057308f;            // -2*sqrt(2/pi)
    constexpr float A2 = -0.071355071222456f;             // 0.044715*C2
    const int gcol = wn * 16 + l15;
    char* gw = smem + GOFF + PAR * 16384;
#pragma unroll
    for (int mt = 0; mt < 2; ++mt) {
#pragma unroll
      for (int r = 0; r < 4; ++r) {
        const float v  = accA[mt][r] + accB[mt][r] + b_cur;
        const float v2 = v * v;
        const float tE = v * __builtin_fmaf(v2, A2, C2);  // = -2u
        const float e  = __expf(tE);
        const float gv = __fdividef(v, 1.f + e);          // v*sigmoid(2u)
        const _Float16 gh = (_Float16)gv;
        const _Float16 gl = (_Float16)(gv - (float)gh);
        const uint32_t pk = (uint32_t)__builtin_bit_cast(unsigned short, gh) |
                            ((uint32_t)__builtin_bit_cast(unsigned short, gl) << 16);
        const int grow = wm * 32 + mt * 16 + lg * 4 + r;
        const uint32_t off = (uint32_t)(grow * 128) +
                             (((uint32_t)(gcol * 4)) ^ ((grow & 7) << 4));
        *(uint32_t*)(gw + off) = pk;
      }
    }
  }
  b_cur = b_nxt;

  // ---- barrier A: all my ds reads/writes retired -> bufs free, G visible ----
  asm volatile("s_waitcnt lgkmcnt(0)" ::: "memory");
  __builtin_amdgcn_s_barrier();
  __builtin_amdgcn_sched_barrier(0);

  // ---- stage next chunks into the freed buffers (8 loads/wave) ----
  if (T < 32) {
    stage_W1(smem, PAR, (T + 2 > 31) ? T : T + 2, w, lane);        // pad: reload T
    stage_W2(smem, PAR ^ 1, (T + 1 > 31) ? 30 : T + 1, w, lane);   // pad: reload 30
  }

  // ---- certify MY W1(T+1)/W2(T) landed, THEN barrier B publishes it ----
  asm volatile("s_waitcnt vmcnt(8)" ::: "memory");
  __builtin_amdgcn_s_barrier();
  __builtin_amdgcn_sched_barrier(0);
}

// ---------------- fused FFN + heads + QR/cov ----------------
__global__ __launch_bounds__(NTHREADS, 2) void fused_kernel(
    const float* __restrict__ x, const float* __restrict__ b1,
    const float* __restrict__ b2, const float* __restrict__ bval,
    const float* __restrict__ bvec, float* __restrict__ out) {
  extern __shared__ char smem[];
  const int tid  = threadIdx.x;
  const int lane = tid & 63;
  const int w    = tid >> 6;     // wave 0..7
  const int wm   = w >> 1;       // row group (32 rows)
  const int wn   = w & 1;        // col group
  const int l15  = lane & 15;
  const int lg   = lane >> 4;
  const int64_t R = (int64_t)blockIdx.x * BM;

  // ---- P0: stage x tile as fp16 hi/lo (row-swizzled) ----
  {
    const float* xg = x + R * KDIM;
#pragma unroll
    for (int i = 0; i < 16; ++i) {
      const int fidx = tid + NTHREADS * i;      // 8192 float4s total
      const int row  = fidx >> 6;
      const int f4   = fidx & 63;
      const float4 v = *(const float4*)(xg + row * KDIM + f4 * 4);
      const _Float16 h0 = (_Float16)v.x, h1 = (_Float16)v.y,
                     h2 = (_Float16)v.z, h3 = (_Float16)v.w;
      f16x4 hv = {h0, h1, h2, h3};
      f16x4 lv = {(_Float16)(v.x - (float)h0), (_Float16)(v.y - (float)h1),
                  (_Float16)(v.z - (float)h2), (_Float16)(v.w - (float)h3)};
      const uint32_t off = (uint32_t)(row * 512) +
                           (((uint32_t)(f4 * 8)) ^ ((row & 7) << 4));
      *(f16x4*)(smem + off)         = hv;
      *(f16x4*)(smem + 65536 + off) = lv;
    }
  }
  __syncthreads();

  // ---- P1: persistent x A-fragments (rows wm*32..+31, all K) ----
  f16x8 xah[2][8], xal[2][8];
#pragma unroll
  for (int mt = 0; mt < 2; ++mt) {
    const int row = wm * 32 + mt * 16 + l15;
    const uint32_t rbase = row * 512;
    const uint32_t swz = (row & 7) << 4;
#pragma unroll
    for (int ks = 0; ks < 8; ++ks) {
      const uint32_t off = rbase + (((uint32_t)((ks * 32 + lg * 8) * 2)) ^ swz);
      xah[mt][ks] = *(const f16x8*)(smem + off);
      xal[mt][ks] = *(const f16x8*)(smem + 65536 + off);
    }
  }
  __syncthreads();   // frag reads drained; vmcnt ledger = 0 after this

  // ---- prologue: bias reg + stage W1(0), W2(0), W1(1)  [12 VMEM/wave] ----
  float b_cur = b1[wn * 16 + l15];
  asm volatile("s_waitcnt vmcnt(0)" ::: "memory");   // b1 scalar load out of ledger
  stage_W1(smem, 0, 0, w, lane);
  stage_W2(smem, 0, 0, w, lane);
  stage_W1(smem, 1, 1, w, lane);
  // certify W1(0) landed (mine), publish via barrier
  asm volatile("s_waitcnt vmcnt(8)" ::: "memory");
  __builtin_amdgcn_s_barrier();
  __builtin_amdgcn_sched_barrier(0);

  const f32x4 z4 = {0.f, 0.f, 0.f, 0.f};
  f32x4 acc2[2][8];
#pragma unroll
  for (int mt = 0; mt < 2; ++mt)
#pragma unroll
    for (int nt = 0; nt < 8; ++nt) acc2[mt][nt] = z4;

  // ---- chunk pipeline: t=0 peeled, then 16 parity pairs (t=1..32) ----
  chunk_body<0, false>(0, smem, xah, xal, acc2, b_cur, b1, wm, wn, l15, lg, w, lane);
#pragma unroll 1
  for (int tt = 0; tt < 16; ++tt) {
    chunk_body<1, true>(2 * tt + 1, smem, xah, xal, acc2, b_cur, b1, wm, wn, l15, lg, w, lane);
    chunk_body<0, true>(2 * tt + 2, smem, xah, xal, acc2, b_cur, b1, wm, wn, l15, lg, w, lane);
  }
  __syncthreads();   // full vmcnt/lgkm drain (tail pad stages) before overlay

  // ---- epilogue: h = x + FFN + b2 (exact f32 residual), write h_hi ----
  {
    const float* xg = x + R * KDIM;
#pragma unroll
    for (int nt = 0; nt < 8; ++nt) {
      const float bv = b2[wn * 128 + nt * 16 + l15];
#pragma unroll
      for (int mt = 0; mt < 2; ++mt) {
#pragma unroll
        for (int r = 0; r < 4; ++r) {
          const int row = wm * 32 + mt * 16 + lg * 4 + r;
          const int col = wn * 128 + nt * 16 + l15;
          const float h = acc2[mt][nt][r] + xg[row * KDIM + col] + bv;
          acc2[mt][nt][r] = h;
          const uint32_t off = (uint32_t)(row * 512) +
                               (((uint32_t)(col * 2)) ^ ((row & 7) << 4));
          *(_Float16*)(smem + off) = (_Float16)h;
        }
      }
    }
  }
  __syncthreads();

  // ---- head GEMM pass 1+2: hh*Whh + hh*Whl ----
  f32x4 hacc = z4;
  const int hrow = wm * 32 + wn * 16 + l15;    // each wave owns 16 token rows
  const uint32_t hbase = hrow * 512;
  const uint32_t hswz  = (hrow & 7) << 4;
#pragma unroll
  for (int ks = 0; ks < 8; ++ks) {
    const uint32_t off = hbase + (((uint32_t)((ks * 32 + lg * 8) * 2)) ^ hswz);
    const f16x8 af  = *(const f16x8*)(smem + off);
    const f16x8 bhf = *(const f16x8*)(g_Whh + l15 * 256 + ks * 32 + lg * 8);
    const f16x8 blf = *(const f16x8*)(g_Whl + l15 * 256 + ks * 32 + lg * 8);
    hacc = MFMA16(af, bhf, hacc);
    hacc = MFMA16(af, blf, hacc);
  }
  __syncthreads();

  // ---- write h_lo over the same buffer ----
#pragma unroll
  for (int nt = 0; nt < 8; ++nt) {
#pragma unroll
    for (int mt = 0; mt < 2; ++mt) {
#pragma unroll
      for (int r = 0; r < 4; ++r) {
        const int row = wm * 32 + mt * 16 + lg * 4 + r;
        const int col = wn * 128 + nt * 16 + l15;
        const float h = acc2[mt][nt][r];
        const _Float16 hh = (_Float16)h;
        const uint32_t off = (uint32_t)(row * 512) +
                             (((uint32_t)(col * 2)) ^ ((row & 7) << 4));
        *(_Float16*)(smem + off) = (_Float16)(h - (float)hh);
      }
    }
  }
  __syncthreads();

  // ---- head pass 3: hl*Whh ----
#pragma unroll
  for (int ks = 0; ks < 8; ++ks) {
    const uint32_t off = hbase + (((uint32_t)((ks * 32 + lg * 8) * 2)) ^ hswz);
    const f16x8 af  = *(const f16x8*)(smem + off);
    const f16x8 bhf = *(const f16x8*)(g_Whh + l15 * 256 + ks * 32 + lg * 8);
    hacc = MFMA16(af, bhf, hacc);
  }
  const float hb = (l15 < 3) ? bval[l15] : ((l15 < 12) ? bvec[l15 - 3] : 0.f);
#pragma unroll
  for (int r = 0; r < 4; ++r) hacc[r] += hb;

  // ---- gather 12 head values per token, QR + cov ----
  float* hstg = (float*)(smem + 65536);   // disjoint from h buffer
#pragma unroll
  for (int r = 0; r < 4; ++r) {
    const int row = wm * 32 + wn * 16 + lg * 4 + r;
    hstg[row * 16 + l15] = hacc[r];
  }
  if (lane < 16) {
    const int row = wm * 32 + wn * 16 + lane;
    const float* hs = hstg + row * 16;
    float sp[3];
#pragma unroll
    for (int i = 0; i < 3; ++i) {
      const float s = hs[i];
      sp[i] = fmaxf(s, 0.f) + log1pf(__expf(-fabsf(s)));   // softplus
    }
    const float a0 = hs[3], a1 = hs[6], a2 = hs[9];
    const float b0 = hs[4], bc1 = hs[7], bc2 = hs[10];
    const float na = a0 * a0 + a1 * a1 + a2 * a2;
    const float ia = 1.f / sqrtf(fmaxf(na, 1e-30f));
    const float q00 = a0 * ia, q01 = a1 * ia, q02 = a2 * ia;
    const float d  = q00 * b0 + q01 * bc1 + q02 * bc2;
    const float u0 = b0 - d * q00, u1 = bc1 - d * q01, u2 = bc2 - d * q02;
    const float nu = u0 * u0 + u1 * u1 + u2 * u2;
    const float iu = 1.f / sqrtf(fmaxf(nu, 1e-30f));
    const float q10 = u0 * iu, q11 = u1 * iu, q12 = u2 * iu;
    const float q20 = q01 * q12 - q02 * q11;
    const float q21 = q02 * q10 - q00 * q12;
    const float q22 = q00 * q11 - q01 * q10;
    const float c00 = sp[0]*q00*q00 + sp[1]*q10*q10 + sp[2]*q20*q20 + 1e-8f;
    const float c11 = sp[0]*q01*q01 + sp[1]*q11*q11 + sp[2]*q21*q21 + 1e-8f;
    const float c22 = sp[0]*q02*q02 + sp[1]*q12*q12 + sp[2]*q22*q22 + 1e-8f;
    const float c01 = sp[0]*q00*q01 + sp[1]*q10*q11 + sp[2]*q20*q21;
    const float c02 = sp[0]*q00*q02 + sp[1]*q10*q12 + sp[2]*q20*q22;
    const float c12 = sp[0]*q01*q02 + sp[1]*q11*q12 + sp[2]*q21*q22;
    float* o = out + (size_t)(R + row) * 9;
    o[0] = c00; o[1] = c01; o[2] = c02;
    o[3] = c01; o[4] = c11; o[5] = c12;
    o[6] = c02; o[7] = c12; o[8] = c22;
  }
}

extern "C" void kernel_launch(void* const* d_in, const int* in_sizes, int n_in,
                              void* d_out, int out_size, void* d_ws, size_t ws_size,
                              hipStream_t stream) {
  const float* x    = (const float*)d_in[0];
  const float* W1   = (const float*)d_in[1];
  const float* b1   = (const float*)d_in[2];
  const float* W2   = (const float*)d_in[3];
  const float* b2   = (const float*)d_in[4];
  const float* Wval = (const float*)d_in[5];
  const float* bval = (const float*)d_in[6];
  const float* Wvec = (const float*)d_in[7];
  const float* bvec = (const float*)d_in[8];
  float* out = (float*)d_out;
  (void)in_sizes; (void)n_in; (void)out_size; (void)d_ws; (void)ws_size;

  hipFuncSetAttribute((const void*)fused_kernel,
                      hipFuncAttributeMaxDynamicSharedMemorySize, LDS_BYTES);

  prep_kernel<<<272, 256, 0, stream>>>(W1, W2, Wval, Wvec);
  fused_kernel<<<NBLOCKS, NTHREADS, LDS_BYTES, stream>>>(x, b1, b2, bval, bvec, out);
}

// Round 5
// 375.146 us; speedup vs baseline: 1.0240x; 1.0240x over previous
//
#include <hip/hip_runtime.h>
#include <cstdint>
#include <cstddef>

// ---------------- problem constants ----------------
#define TOKENS   65536      // B*N = 16*4096
#define KDIM     256        // model dim
#define HIDDEN   1024       // 4*dim
#define BM       128        // tokens per block
#define HC       32         // hidden chunk width
#define NCHUNK   32         // HIDDEN / HC
#define NTHREADS 512        // 8 waves
#define NBLOCKS  (TOKENS / BM)

// LDS map (160 KB dynamic, exactly the CU's LDS):
//   W1buf[2] @0      : each 32K = W1h 16K | W1l 16K      (64 KB)
//   W2buf[2] @65536  : each 32K = W2h 16K | W2l 16K      (64 KB)
//   G[2]     @131072 : each 16K = u32-packed (gh|gl<<16) [128][32]
//   P0 overlay: x_hi @0..64K, x_lo @64K..128K (pre-loop only)
//   epilogue:  h fp16 @0..64K ; hstg f32[128][16] @65536
#define W2OFF 65536
#define GOFF  131072
#define LDS_BYTES 163840

using f16x8 = __attribute__((ext_vector_type(8))) _Float16;
using f16x4 = __attribute__((ext_vector_type(4))) _Float16;
using f32x4 = __attribute__((ext_vector_type(4))) float;
using u32x4 = __attribute__((ext_vector_type(4))) uint32_t;

// fp16 hi/lo split weights, pre-transposed + pre-swizzled per chunk so a
// LINEAR global_load_lds stage produces the swizzled LDS image directly.
// W1 plane: [c][n=32][k=256], byte = n*512 + ((g*16) ^ ((n&7)<<4))
// W2 plane: [c][n=256][k=32], byte = n*64  + ((g*16) ^ (((n>>1)&3)<<4))
__device__ __align__(16) _Float16 g_W1h[NCHUNK * HC * KDIM];
__device__ __align__(16) _Float16 g_W1l[NCHUNK * HC * KDIM];
__device__ __align__(16) _Float16 g_W2h[NCHUNK * KDIM * HC];
__device__ __align__(16) _Float16 g_W2l[NCHUNK * KDIM * HC];
__device__ __align__(16) _Float16 g_Whh[16 * KDIM];            // head rows j(16) x k(256)
__device__ __align__(16) _Float16 g_Whl[16 * KDIM];

// ---------------- prep: split + transpose + swizzle (dest-coalesced) ----------------
__global__ __launch_bounds__(256) void prep_kernel(
    const float* __restrict__ W1, const float* __restrict__ W2,
    const float* __restrict__ Wval, const float* __restrict__ Wvec) {
  const int tid = blockIdx.x * 256 + threadIdx.x;
  if (tid < 32768) {
    // W1: c(32) x n(32) x gd(32 dest k-octets)
    const int c = tid >> 10, n = (tid >> 5) & 31, gd = tid & 31;
    const int g = gd ^ (n & 7);          // swizzle is involutive on octet index
    const int hid = c * 32 + n;
    f16x8 hv, lv;
#pragma unroll
    for (int j = 0; j < 8; ++j) {
      const float wv = W1[(g * 8 + j) * HIDDEN + hid];
      const _Float16 hi = (_Float16)wv;
      hv[j] = hi;
      lv[j] = (_Float16)(wv - (float)hi);
    }
    const int dst = c * 8192 + n * 256 + gd * 8;
    *(f16x8*)(g_W1h + dst) = hv;
    *(f16x8*)(g_W1l + dst) = lv;
  } else if (tid < 65536) {
    // W2: c(32) x n(256) x gd(4)
    const int t = tid - 32768;
    const int c = t >> 10, n = (t >> 2) & 255, gd = t & 3;
    const int g = gd ^ ((n >> 1) & 3);
    f16x8 hv, lv;
#pragma unroll
    for (int j = 0; j < 8; ++j) {
      const float wv = W2[(c * 32 + g * 8 + j) * KDIM + n];
      const _Float16 hi = (_Float16)wv;
      hv[j] = hi;
      lv[j] = (_Float16)(wv - (float)hi);
    }
    const int dst = c * 8192 + n * 32 + gd * 8;
    *(f16x8*)(g_W2h + dst) = hv;
    *(f16x8*)(g_W2l + dst) = lv;
  } else if (tid < 65536 + 4096) {
    const int e = tid - 65536;
    const int j16 = e >> 8, k = e & 255;
    float wv = 0.f;
    if (j16 < 3) wv = Wval[k * 3 + j16];
    else if (j16 < 12) wv = Wvec[k * 9 + (j16 - 3)];
    const _Float16 hi = (_Float16)wv;
    g_Whh[e] = hi;
    g_Whl[e] = (_Float16)(wv - (float)hi);
  }
}

// stage one 32KB W-pair (h+l planes): 8 waves x 4KB = 4x 1KB loads per wave.
// EXACTLY 4 VMEM ops per wave -> vmcnt ledger stays exact.
__device__ __forceinline__ void stage_W1(char* smem, int par, int c, int w, int lane) {
  const char* base = (w < 4) ? (const char*)g_W1h : (const char*)g_W1l;
  const char* s = base + (size_t)c * 16384 + (size_t)(w & 3) * 4096 + (size_t)lane * 16;
  char* d = smem + par * 32768 + ((w < 4) ? 0 : 16384) + (w & 3) * 4096;
#pragma unroll
  for (int i = 0; i < 4; ++i) {
    __builtin_amdgcn_global_load_lds(
        (__attribute__((address_space(1))) void*)(void*)(s + i * 1024),
        (__attribute__((address_space(3))) void*)(d + i * 1024), 16, 0, 0);
  }
}
__device__ __forceinline__ void stage_W2(char* smem, int par, int c, int w, int lane) {
  const char* base = (w < 4) ? (const char*)g_W2h : (const char*)g_W2l;
  const char* s = base + (size_t)c * 16384 + (size_t)(w & 3) * 4096 + (size_t)lane * 16;
  char* d = smem + W2OFF + par * 32768 + ((w < 4) ? 0 : 16384) + (w & 3) * 4096;
#pragma unroll
  for (int i = 0; i < 4; ++i) {
    __builtin_amdgcn_global_load_lds(
        (__attribute__((address_space(1))) void*)(void*)(s + i * 1024),
        (__attribute__((address_space(3))) void*)(d + i * 1024), 16, 0, 0);
  }
}

__device__ __forceinline__ f16x8 unpack_half(const u32x4 a, const u32x4 b, uint32_t sel) {
  u32x4 r;
  r[0] = __builtin_amdgcn_perm(a[1], a[0], sel);
  r[1] = __builtin_amdgcn_perm(a[3], a[2], sel);
  r[2] = __builtin_amdgcn_perm(b[1], b[0], sel);
  r[3] = __builtin_amdgcn_perm(b[3], b[2], sel);
  return __builtin_bit_cast(f16x8, r);
}

#define MFMA16(a, b, c) __builtin_amdgcn_mfma_f32_16x16x32_f16((a), (b), (c), 0, 0, 0)

// One chunk iteration. PAR = t&1 (compile-time). DO_G2: GEMM2 of chunk t-1.
// Runtime guard (T<32) disables GEMM1/GELU/stage on the final drain iteration.
//
// Sync contract (R4-verified, cross-wave-safe):
//   entry: ALL waves' W1(T)/W2(T-1) DMAs certified landed (barrier B of T-1).
//   body order (register-liveness-minimizing): GEMM1(T) -> GELU(T) retires
//   accA/accB into packed G words -> GEMM2(T-1).
//   barrier A = my ds reads/writes retired (bufs free, G[PAR] visible);
//   stage into freed bufs; vmcnt(8) certifies MY W1(T+1)/W2(T) landed;
//   barrier B publishes that certification to all waves.
template <int PAR, bool DO_G2>
__device__ __forceinline__ void chunk_body(
    int T, char* __restrict__ smem,
    const f16x8 (&xah)[2][8], const f16x8 (&xal)[2][8],
    f32x4 (&acc2)[2][8], float& b_cur, const float* __restrict__ b1g,
    int wm, int wn, int l15, int lg, int w, int lane) {
  const f32x4 z4 = {0.f, 0.f, 0.f, 0.f};

  float b_nxt = 0.f;
  if (T < 32) {
    const int idx = (((T + 1) & 31) * 32) + wn * 16 + l15;  // T=31 -> chunk0 (unused)
    b_nxt = b1g[idx];                    // 1 VMEM op, accounted in the ledger
  }

  // ---- GEMM1(T): accA = xh*W1h ; accB = xh*W1l + xl*W1h (chained) ----
  f32x4 accA[2] = {z4, z4}, accB[2] = {z4, z4};
  if (T < 32) {
    const int n = wn * 16 + l15;
    const uint32_t nbase = (uint32_t)(n * 512);
    const uint32_t nswz  = (uint32_t)((n & 7) << 4);
    const char* w1b = smem + PAR * 32768;
    __builtin_amdgcn_s_setprio(1);
#pragma unroll
    for (int ks = 0; ks < 8; ++ks) {
      const uint32_t off = nbase + (((uint32_t)(ks * 64 + lg * 16)) ^ nswz);
      const f16x8 bh = *(const f16x8*)(w1b + off);
      const f16x8 bl = *(const f16x8*)(w1b + 16384 + off);
#pragma unroll
      for (int mt = 0; mt < 2; ++mt) {
        accA[mt] = MFMA16(xah[mt][ks], bh, accA[mt]);
        accB[mt] = MFMA16(xah[mt][ks], bl, accB[mt]);
        accB[mt] = MFMA16(xal[mt][ks], bh, accB[mt]);
      }
    }
    __builtin_amdgcn_s_setprio(0);
  }

  // ---- GELU(T): retire accA/accB NOW (before GEMM2 operands go live) ----
  if (T < 32) {
    constexpr float C2 = -1.5957691216057308f;            // -2*sqrt(2/pi)
    constexpr float A2 = -0.071355071222456f;             // 0.044715*C2
    const int gcol = wn * 16 + l15;
    char* gw = smem + GOFF + PAR * 16384;
#pragma unroll
    for (int mt = 0; mt < 2; ++mt) {
#pragma unroll
      for (int r = 0; r < 4; ++r) {
        const float v  = accA[mt][r] + accB[mt][r] + b_cur;
        const float v2 = v * v;
        const float tE = v * __builtin_fmaf(v2, A2, C2);  // = -2u
        const float e  = __expf(tE);
        const float gv = __fdividef(v, 1.f + e);          // v*sigmoid(2u)
        const _Float16 gh = (_Float16)gv;
        const _Float16 gl = (_Float16)(gv - (float)gh);
        const uint32_t pk = (uint32_t)__builtin_bit_cast(unsigned short, gh) |
                            ((uint32_t)__builtin_bit_cast(unsigned short, gl) << 16);
        const int grow = wm * 32 + mt * 16 + lg * 4 + r;
        const uint32_t off = (uint32_t)(grow * 128) +
                             (((uint32_t)(gcol * 4)) ^ ((grow & 7) << 4));
        *(uint32_t*)(gw + off) = pk;
      }
    }
  }
  b_cur = b_nxt;

  // ---- GEMM2(T-1): acc2 += gh*W2h + gh*W2l + gl*W2h (prev chunk's G) ----
  if (DO_G2) {
    const char* w2b = smem + W2OFF + (PAR ^ 1) * 32768;
    const char* gb  = smem + GOFF + (PAR ^ 1) * 16384;
    f16x8 ah[2], al[2];
#pragma unroll
    for (int mt = 0; mt < 2; ++mt) {
      const int row = wm * 32 + mt * 16 + l15;
      const uint32_t sw = (uint32_t)((row & 7) << 4);
      const uint32_t base = (uint32_t)(row * 128);
      const u32x4 w0 = *(const u32x4*)(gb + base + (((uint32_t)(lg * 32)) ^ sw));
      const u32x4 w1v = *(const u32x4*)(gb + base + (((uint32_t)(lg * 32 + 16)) ^ sw));
      ah[mt] = unpack_half(w0, w1v, 0x05040100u);   // gh lanes
      al[mt] = unpack_half(w0, w1v, 0x07060302u);   // gl lanes
    }
    __builtin_amdgcn_s_setprio(1);
#pragma unroll
    for (int nt = 0; nt < 8; ++nt) {
      const int n = wn * 128 + nt * 16 + l15;
      const uint32_t off = (uint32_t)(n * 64) +
                           (((uint32_t)(lg * 16)) ^ (((n >> 1) & 3) << 4));
      const f16x8 bh = *(const f16x8*)(w2b + off);
      const f16x8 bl = *(const f16x8*)(w2b + 16384 + off);
#pragma unroll
      for (int mt = 0; mt < 2; ++mt) {
        acc2[mt][nt] = MFMA16(ah[mt], bh, acc2[mt][nt]);
        acc2[mt][nt] = MFMA16(ah[mt], bl, acc2[mt][nt]);
        acc2[mt][nt] = MFMA16(al[mt], bh, acc2[mt][nt]);
      }
    }
    __builtin_amdgcn_s_setprio(0);
  }

  // ---- barrier A: all my ds reads/writes retired -> bufs free, G visible ----
  asm volatile("s_waitcnt lgkmcnt(0)" ::: "memory");
  __builtin_amdgcn_s_barrier();
  __builtin_amdgcn_sched_barrier(0);

  // ---- stage next chunks into the freed buffers (8 loads/wave) ----
  if (T < 32) {
    stage_W1(smem, PAR, (T + 2 > 31) ? T : T + 2, w, lane);        // pad: reload T
    stage_W2(smem, PAR ^ 1, (T + 1 > 31) ? 30 : T + 1, w, lane);   // pad: reload 30
  }

  // ---- certify MY W1(T+1)/W2(T) landed, THEN barrier B publishes it ----
  asm volatile("s_waitcnt vmcnt(8)" ::: "memory");
  __builtin_amdgcn_s_barrier();
  __builtin_amdgcn_sched_barrier(0);
}

// ---------------- fused FFN + heads + QR/cov ----------------
__global__ __launch_bounds__(NTHREADS, 2) void fused_kernel(
    const float* __restrict__ x, const float* __restrict__ b1,
    const float* __restrict__ b2, const float* __restrict__ bval,
    const float* __restrict__ bvec, float* __restrict__ out) {
  extern __shared__ char smem[];
  const int tid  = threadIdx.x;
  const int lane = tid & 63;
  const int w    = tid >> 6;     // wave 0..7
  const int wm   = w >> 1;       // row group (32 rows)
  const int wn   = w & 1;        // col group
  const int l15  = lane & 15;
  const int lg   = lane >> 4;
  const int64_t R = (int64_t)blockIdx.x * BM;

  // ---- P0: stage x tile as fp16 hi/lo (row-swizzled) ----
  {
    const float* xg = x + R * KDIM;
#pragma unroll
    for (int i = 0; i < 16; ++i) {
      const int fidx = tid + NTHREADS * i;      // 8192 float4s total
      const int row  = fidx >> 6;
      const int f4   = fidx & 63;
      const float4 v = *(const float4*)(xg + row * KDIM + f4 * 4);
      const _Float16 h0 = (_Float16)v.x, h1 = (_Float16)v.y,
                     h2 = (_Float16)v.z, h3 = (_Float16)v.w;
      f16x4 hv = {h0, h1, h2, h3};
      f16x4 lv = {(_Float16)(v.x - (float)h0), (_Float16)(v.y - (float)h1),
                  (_Float16)(v.z - (float)h2), (_Float16)(v.w - (float)h3)};
      const uint32_t off = (uint32_t)(row * 512) +
                           (((uint32_t)(f4 * 8)) ^ ((row & 7) << 4));
      *(f16x4*)(smem + off)         = hv;
      *(f16x4*)(smem + 65536 + off) = lv;
    }
  }
  __syncthreads();

  // ---- P1: persistent x A-fragments (rows wm*32..+31, all K) ----
  f16x8 xah[2][8], xal[2][8];
#pragma unroll
  for (int mt = 0; mt < 2; ++mt) {
    const int row = wm * 32 + mt * 16 + l15;
    const uint32_t rbase = row * 512;
    const uint32_t swz = (row & 7) << 4;
#pragma unroll
    for (int ks = 0; ks < 8; ++ks) {
      const uint32_t off = rbase + (((uint32_t)((ks * 32 + lg * 8) * 2)) ^ swz);
      xah[mt][ks] = *(const f16x8*)(smem + off);
      xal[mt][ks] = *(const f16x8*)(smem + 65536 + off);
    }
  }
  __syncthreads();   // frag reads drained; vmcnt ledger = 0 after this

  // ---- prologue: bias reg + stage W1(0), W2(0), W1(1)  [12 VMEM/wave] ----
  float b_cur = b1[wn * 16 + l15];
  asm volatile("s_waitcnt vmcnt(0)" ::: "memory");   // b1 scalar load out of ledger
  stage_W1(smem, 0, 0, w, lane);
  stage_W2(smem, 0, 0, w, lane);
  stage_W1(smem, 1, 1, w, lane);
  // certify W1(0) landed (mine), publish via barrier
  asm volatile("s_waitcnt vmcnt(8)" ::: "memory");
  __builtin_amdgcn_s_barrier();
  __builtin_amdgcn_sched_barrier(0);

  const f32x4 z4 = {0.f, 0.f, 0.f, 0.f};
  f32x4 acc2[2][8];
#pragma unroll
  for (int mt = 0; mt < 2; ++mt)
#pragma unroll
    for (int nt = 0; nt < 8; ++nt) acc2[mt][nt] = z4;

  // ---- chunk pipeline: t=0 peeled, then 16 parity pairs (t=1..32) ----
  chunk_body<0, false>(0, smem, xah, xal, acc2, b_cur, b1, wm, wn, l15, lg, w, lane);
#pragma unroll 1
  for (int tt = 0; tt < 16; ++tt) {
    chunk_body<1, true>(2 * tt + 1, smem, xah, xal, acc2, b_cur, b1, wm, wn, l15, lg, w, lane);
    chunk_body<0, true>(2 * tt + 2, smem, xah, xal, acc2, b_cur, b1, wm, wn, l15, lg, w, lane);
  }
  __syncthreads();   // full vmcnt/lgkm drain (tail pad stages) before overlay

  // ---- epilogue: h = x + FFN + b2 (exact f32 residual), write h_hi ----
  {
    const float* xg = x + R * KDIM;
#pragma unroll
    for (int nt = 0; nt < 8; ++nt) {
      const float bv = b2[wn * 128 + nt * 16 + l15];
#pragma unroll
      for (int mt = 0; mt < 2; ++mt) {
#pragma unroll
        for (int r = 0; r < 4; ++r) {
          const int row = wm * 32 + mt * 16 + lg * 4 + r;
          const int col = wn * 128 + nt * 16 + l15;
          const float h = acc2[mt][nt][r] + xg[row * KDIM + col] + bv;
          acc2[mt][nt][r] = h;
          const uint32_t off = (uint32_t)(row * 512) +
                               (((uint32_t)(col * 2)) ^ ((row & 7) << 4));
          *(_Float16*)(smem + off) = (_Float16)h;
        }
      }
    }
  }
  __syncthreads();

  // ---- head GEMM pass 1+2: hh*Whh + hh*Whl ----
  f32x4 hacc = z4;
  const int hrow = wm * 32 + wn * 16 + l15;    // each wave owns 16 token rows
  const uint32_t hbase = hrow * 512;
  const uint32_t hswz  = (hrow & 7) << 4;
#pragma unroll
  for (int ks = 0; ks < 8; ++ks) {
    const uint32_t off = hbase + (((uint32_t)((ks * 32 + lg * 8) * 2)) ^ hswz);
    const f16x8 af  = *(const f16x8*)(smem + off);
    const f16x8 bhf = *(const f16x8*)(g_Whh + l15 * 256 + ks * 32 + lg * 8);
    const f16x8 blf = *(const f16x8*)(g_Whl + l15 * 256 + ks * 32 + lg * 8);
    hacc = MFMA16(af, bhf, hacc);
    hacc = MFMA16(af, blf, hacc);
  }
  __syncthreads();

  // ---- write h_lo over the same buffer ----
#pragma unroll
  for (int nt = 0; nt < 8; ++nt) {
#pragma unroll
    for (int mt = 0; mt < 2; ++mt) {
#pragma unroll
      for (int r = 0; r < 4; ++r) {
        const int row = wm * 32 + mt * 16 + lg * 4 + r;
        const int col = wn * 128 + nt * 16 + l15;
        const float h = acc2[mt][nt][r];
        const _Float16 hh = (_Float16)h;
        const uint32_t off = (uint32_t)(row * 512) +
                             (((uint32_t)(col * 2)) ^ ((row & 7) << 4));
        *(_Float16*)(smem + off) = (_Float16)(h - (float)hh);
      }
    }
  }
  __syncthreads();

  // ---- head pass 3: hl*Whh ----
#pragma unroll
  for (int ks = 0; ks < 8; ++ks) {
    const uint32_t off = hbase + (((uint32_t)((ks * 32 + lg * 8) * 2)) ^ hswz);
    const f16x8 af  = *(const f16x8*)(smem + off);
    const f16x8 bhf = *(const f16x8*)(g_Whh + l15 * 256 + ks * 32 + lg * 8);
    hacc = MFMA16(af, bhf, hacc);
  }
  const float hb = (l15 < 3) ? bval[l15] : ((l15 < 12) ? bvec[l15 - 3] : 0.f);
#pragma unroll
  for (int r = 0; r < 4; ++r) hacc[r] += hb;

  // ---- gather 12 head values per token, QR + cov ----
  float* hstg = (float*)(smem + 65536);   // disjoint from h buffer
#pragma unroll
  for (int r = 0; r < 4; ++r) {
    const int row = wm * 32 + wn * 16 + lg * 4 + r;
    hstg[row * 16 + l15] = hacc[r];
  }
  if (lane < 16) {
    const int row = wm * 32 + wn * 16 + lane;
    const float* hs = hstg + row * 16;
    float sp[3];
#pragma unroll
    for (int i = 0; i < 3; ++i) {
      const float s = hs[i];
      sp[i] = fmaxf(s, 0.f) + log1pf(__expf(-fabsf(s)));   // softplus
    }
    const float a0 = hs[3], a1 = hs[6], a2 = hs[9];
    const float b0 = hs[4], bc1 = hs[7], bc2 = hs[10];
    const float na = a0 * a0 + a1 * a1 + a2 * a2;
    const float ia = 1.f / sqrtf(fmaxf(na, 1e-30f));
    const float q00 = a0 * ia, q01 = a1 * ia, q02 = a2 * ia;
    const float d  = q00 * b0 + q01 * bc1 + q02 * bc2;
    const float u0 = b0 - d * q00, u1 = bc1 - d * q01, u2 = bc2 - d * q02;
    const float nu = u0 * u0 + u1 * u1 + u2 * u2;
    const float iu = 1.f / sqrtf(fmaxf(nu, 1e-30f));
    const float q10 = u0 * iu, q11 = u1 * iu, q12 = u2 * iu;
    const float q20 = q01 * q12 - q02 * q11;
    const float q21 = q02 * q10 - q00 * q12;
    const float q22 = q00 * q11 - q01 * q10;
    const float c00 = sp[0]*q00*q00 + sp[1]*q10*q10 + sp[2]*q20*q20 + 1e-8f;
    const float c11 = sp[0]*q01*q01 + sp[1]*q11*q11 + sp[2]*q21*q21 + 1e-8f;
    const float c22 = sp[0]*q02*q02 + sp[1]*q12*q12 + sp[2]*q22*q22 + 1e-8f;
    const float c01 = sp[0]*q00*q01 + sp[1]*q10*q11 + sp[2]*q20*q21;
    const float c02 = sp[0]*q00*q02 + sp[1]*q10*q12 + sp[2]*q20*q22;
    const float c12 = sp[0]*q01*q02 + sp[1]*q11*q12 + sp[2]*q21*q22;
    float* o = out + (size_t)(R + row) * 9;
    o[0] = c00; o[1] = c01; o[2] = c02;
    o[3] = c01; o[4] = c11; o[5] = c12;
    o[6] = c02; o[7] = c12; o[8] = c22;
  }
}

extern "C" void kernel_launch(void* const* d_in, const int* in_sizes, int n_in,
                              void* d_out, int out_size, void* d_ws, size_t ws_size,
                              hipStream_t stream) {
  const float* x    = (const float*)d_in[0];
  const float* W1   = (const float*)d_in[1];
  const float* b1   = (const float*)d_in[2];
  const float* W2   = (const float*)d_in[3];
  const float* b2   = (const float*)d_in[4];
  const float* Wval = (const float*)d_in[5];
  const float* bval = (const float*)d_in[6];
  const float* Wvec = (const float*)d_in[7];
  const float* bvec = (const float*)d_in[8];
  float* out = (float*)d_out;
  (void)in_sizes; (void)n_in; (void)out_size; (void)d_ws; (void)ws_size;

  hipFuncSetAttribute((const void*)fused_kernel,
                      hipFuncAttributeMaxDynamicSharedMemorySize, LDS_BYTES);

  prep_kernel<<<272, 256, 0, stream>>>(W1, W2, Wval, Wvec);
  fused_kernel<<<NBLOCKS, NTHREADS, LDS_BYTES, stream>>>(x, b1, b2, bval, bvec, out);
}

// Round 7
// 319.544 us; speedup vs baseline: 1.2022x; 1.1740x over previous
//
#include <hip/hip_runtime.h>
#include <cstdint>
#include <cstddef>

// ---------------- problem constants ----------------
#define TOKENS   65536      // B*N = 16*4096
#define KDIM     256        // model dim
#define HIDDEN   1024       // 4*dim
#define BM       128        // tokens per block
#define HC       32         // hidden chunk width
#define NCHUNK   32         // HIDDEN / HC
#define NTHREADS 512        // 8 waves
#define NBLOCKS  (TOKENS / BM)

// LDS map (131072 B dynamic; sized by the P0 x-overlay):
//   steady state:
//     W1  @0      : 16K h | 16K l   (single buffer, restaged after barrier1)
//     W2  @32768  : 16K h | 16K l   (single buffer, restaged at loop top)
//     G   @65536  : 16K u32-packed (gh|gl<<16) [128][32]
//     accC@81920  : 16K f32 [128][32]  (xl*W1h partial, wave-plane1 -> plane0)
//     b1  @98304  : 4K f32[1024]
//   P0 overlay: x_hi @0..64K, x_lo @64K..128K (pre-loop only)
//   epilogue:  h fp16 @0..64K ; hstg f32[128][16] @65536
#define W2OFF  32768
#define GOFF   65536
#define ACCOFF 81920
#define B1OFF  98304
#define LDS_BYTES 131072

using f16x8 = __attribute__((ext_vector_type(8))) _Float16;
using f16x4 = __attribute__((ext_vector_type(4))) _Float16;
using f32x4 = __attribute__((ext_vector_type(4))) float;
using u32x4 = __attribute__((ext_vector_type(4))) uint32_t;

// fp16 hi/lo split weights, pre-transposed + pre-swizzled per chunk so a
// LINEAR global_load_lds stage produces the swizzled LDS image directly.
// W1 plane: [c][n=32][k=256], byte = n*512 + ((g*16) ^ ((n&7)<<4))
// W2 plane: [c][n=256][k=32], byte = n*64  + ((g*16) ^ (((n>>1)&3)<<4))
__device__ __align__(16) _Float16 g_W1h[NCHUNK * HC * KDIM];
__device__ __align__(16) _Float16 g_W1l[NCHUNK * HC * KDIM];
__device__ __align__(16) _Float16 g_W2h[NCHUNK * KDIM * HC];
__device__ __align__(16) _Float16 g_W2l[NCHUNK * KDIM * HC];
__device__ __align__(16) _Float16 g_Whh[16 * KDIM];            // head rows j(16) x k(256)
__device__ __align__(16) _Float16 g_Whl[16 * KDIM];

// ---------------- prep: split + transpose + swizzle (dest-coalesced) ----------------
__global__ __launch_bounds__(256) void prep_kernel(
    const float* __restrict__ W1, const float* __restrict__ W2,
    const float* __restrict__ Wval, const float* __restrict__ Wvec) {
  const int tid = blockIdx.x * 256 + threadIdx.x;
  if (tid < 32768) {
    // W1: c(32) x n(32) x gd(32 dest k-octets)
    const int c = tid >> 10, n = (tid >> 5) & 31, gd = tid & 31;
    const int g = gd ^ (n & 7);          // swizzle is involutive on octet index
    const int hid = c * 32 + n;
    f16x8 hv, lv;
#pragma unroll
    for (int j = 0; j < 8; ++j) {
      const float wv = W1[(g * 8 + j) * HIDDEN + hid];
      const _Float16 hi = (_Float16)wv;
      hv[j] = hi;
      lv[j] = (_Float16)(wv - (float)hi);
    }
    const int dst = c * 8192 + n * 256 + gd * 8;
    *(f16x8*)(g_W1h + dst) = hv;
    *(f16x8*)(g_W1l + dst) = lv;
  } else if (tid < 65536) {
    // W2: c(32) x n(256) x gd(4)
    const int t = tid - 32768;
    const int c = t >> 10, n = (t >> 2) & 255, gd = t & 3;
    const int g = gd ^ ((n >> 1) & 3);
    f16x8 hv, lv;
#pragma unroll
    for (int j = 0; j < 8; ++j) {
      const float wv = W2[(c * 32 + g * 8 + j) * KDIM + n];
      const _Float16 hi = (_Float16)wv;
      hv[j] = hi;
      lv[j] = (_Float16)(wv - (float)hi);
    }
    const int dst = c * 8192 + n * 32 + gd * 8;
    *(f16x8*)(g_W2h + dst) = hv;
    *(f16x8*)(g_W2l + dst) = lv;
  } else if (tid < 65536 + 4096) {
    const int e = tid - 65536;
    const int j16 = e >> 8, k = e & 255;
    float wv = 0.f;
    if (j16 < 3) wv = Wval[k * 3 + j16];
    else if (j16 < 12) wv = Wvec[k * 9 + (j16 - 3)];
    const _Float16 hi = (_Float16)wv;
    g_Whh[e] = hi;
    g_Whl[e] = (_Float16)(wv - (float)hi);
  }
}

// stage one 32KB W-pair (h+l planes) into its SINGLE buffer:
// 8 waves x 4KB = EXACTLY 4 VMEM ops per wave (ledger-exact).
__device__ __forceinline__ void stage_W1(char* smem, int c, int w, int lane) {
  const char* base = (w < 4) ? (const char*)g_W1h : (const char*)g_W1l;
  const char* s = base + (size_t)c * 16384 + (size_t)(w & 3) * 4096 + (size_t)lane * 16;
  char* d = smem + ((w < 4) ? 0 : 16384) + (w & 3) * 4096;
#pragma unroll
  for (int i = 0; i < 4; ++i) {
    __builtin_amdgcn_global_load_lds(
        (__attribute__((address_space(1))) void*)(void*)(s + i * 1024),
        (__attribute__((address_space(3))) void*)(d + i * 1024), 16, 0, 0);
  }
}
__device__ __forceinline__ void stage_W2(char* smem, int c, int w, int lane) {
  const char* base = (w < 4) ? (const char*)g_W2h : (const char*)g_W2l;
  const char* s = base + (size_t)c * 16384 + (size_t)(w & 3) * 4096 + (size_t)lane * 16;
  char* d = smem + W2OFF + ((w < 4) ? 0 : 16384) + (w & 3) * 4096;
#pragma unroll
  for (int i = 0; i < 4; ++i) {
    __builtin_amdgcn_global_load_lds(
        (__attribute__((address_space(1))) void*)(void*)(s + i * 1024),
        (__attribute__((address_space(3))) void*)(d + i * 1024), 16, 0, 0);
  }
}

__device__ __forceinline__ f16x8 unpack_half(const u32x4 a, const u32x4 b, uint32_t sel) {
  u32x4 r;
  r[0] = __builtin_amdgcn_perm(a[1], a[0], sel);
  r[1] = __builtin_amdgcn_perm(a[3], a[2], sel);
  r[2] = __builtin_amdgcn_perm(b[1], b[0], sel);
  r[3] = __builtin_amdgcn_perm(b[3], b[2], sel);
  return __builtin_bit_cast(f16x8, r);
}

#define MFMA16(a, b, c) __builtin_amdgcn_mfma_f32_16x16x32_f16((a), (b), (c), 0, 0, 0)

// ---------------- fused FFN + heads + QR/cov ----------------
// Wave roles: wm = w&3 owns token rows [32wm,32wm+32).
//   wp = w>>2 == 0: holds x_hi frags; GEMM1 passes xh*W1h, xh*W1l; does GELU.
//   wp == 1:        holds x_lo frags; GEMM1 pass  xl*W1h -> accC via LDS.
// GEMM2: all 8 waves, col half = wp*128.
//
// Per-iter sync (R2-proven vmcnt-before-barrier ordering):
//   top: stage_W2(t) [4 loads]
//   GEMM1 (+accC write)            -> lgkm(0); barrier1
//   if t<31 stage_W1(t+1) [4 loads]
//   GELU (wp==0): accA+accB+accC+b1 -> G
//                                  -> lgkm(0); vmcnt(4 | 0@t=31); barrier2
//        (certifies W2(t): 4 newer W1 loads stay in flight)
//   GEMM2 reads G + W2(t)          -> lgkm(0); vmcnt(0); barrier3
//        (W2 reads retired -> next top may restage; W1(t+1) certified)
__global__ __launch_bounds__(NTHREADS, 2) void fused_kernel(
    const float* __restrict__ x, const float* __restrict__ b1,
    const float* __restrict__ b2, const float* __restrict__ bval,
    const float* __restrict__ bvec, float* __restrict__ out) {
  extern __shared__ char smem[];
  const int tid  = threadIdx.x;
  const int lane = tid & 63;
  const int w    = tid >> 6;     // wave 0..7
  const int wm   = w & 3;        // row group (32 rows)
  const int wp   = w >> 2;       // plane/role (GEMM1), col half (GEMM2)
  const int l15  = lane & 15;
  const int lg   = lane >> 4;
  const int64_t R = (int64_t)blockIdx.x * BM;

  // ---- P0: stage x tile as fp16 hi/lo (row-swizzled) ----
  {
    const float* xg = x + R * KDIM;
#pragma unroll
    for (int i = 0; i < 16; ++i) {
      const int fidx = tid + NTHREADS * i;      // 8192 float4s total
      const int row  = fidx >> 6;
      const int f4   = fidx & 63;
      const float4 v = *(const float4*)(xg + row * KDIM + f4 * 4);
      const _Float16 h0 = (_Float16)v.x, h1 = (_Float16)v.y,
                     h2 = (_Float16)v.z, h3 = (_Float16)v.w;
      f16x4 hv = {h0, h1, h2, h3};
      f16x4 lv = {(_Float16)(v.x - (float)h0), (_Float16)(v.y - (float)h1),
                  (_Float16)(v.z - (float)h2), (_Float16)(v.w - (float)h3)};
      const uint32_t off = (uint32_t)(row * 512) +
                           (((uint32_t)(f4 * 8)) ^ ((row & 7) << 4));
      *(f16x4*)(smem + off)         = hv;
      *(f16x4*)(smem + 65536 + off) = lv;
    }
  }
  __syncthreads();

  // ---- P1: per-wave x A-fragments, ONE plane (wp) only: 64 VGPR ----
  f16x8 xa[2][8];
  {
    const char* xplane = smem + wp * 65536;
#pragma unroll
    for (int mt = 0; mt < 2; ++mt) {
      const int row = wm * 32 + mt * 16 + l15;
      const uint32_t rbase = row * 512;
      const uint32_t swz = (row & 7) << 4;
#pragma unroll
      for (int ks = 0; ks < 8; ++ks) {
        const uint32_t off = rbase + (((uint32_t)((ks * 32 + lg * 8) * 2)) ^ swz);
        xa[mt][ks] = *(const f16x8*)(xplane + off);
      }
    }
  }
  __syncthreads();   // x reads drained; overlay area free

  // ---- prologue: b1 -> LDS, stage W1(0); full drain before loop ----
  {
    float* b1l = (float*)(smem + B1OFF);
    b1l[tid]       = b1[tid];
    b1l[tid + 512] = b1[tid + 512];
  }
  stage_W1(smem, 0, w, lane);
  __syncthreads();   // full vmcnt/lgkm drain: W1(0)+b1 in LDS for all waves

  const f32x4 z4 = {0.f, 0.f, 0.f, 0.f};
  f32x4 acc2[2][8];
#pragma unroll
  for (int mt = 0; mt < 2; ++mt)
#pragma unroll
    for (int nt = 0; nt < 8; ++nt) acc2[mt][nt] = z4;

  // ---- chunk loop: 3-barrier lockstep, single-buffered weights ----
#pragma unroll 1
  for (int t = 0; t < NCHUNK; ++t) {
    stage_W2(smem, t, w, lane);            // 4 loads; certified at barrier2

    // ---- GEMM1(t): plane-split ----
    // accG[0..3] = {A (wp0) or C (wp1)}[nt*2+mt]; accG[4..7] = B[nt*2+mt] (wp0)
    f32x4 accG[8] = {z4, z4, z4, z4, z4, z4, z4, z4};
    {
      const uint32_t swz   = (uint32_t)((l15 & 7) << 4);
      const uint32_t base0 = (uint32_t)(l15 * 512);
      const uint32_t base1 = (uint32_t)((16 + l15) * 512);
      if (wp == 0) {
#pragma unroll
        for (int ks = 0; ks < 8; ++ks) {
          const uint32_t off = ((uint32_t)(ks * 64 + lg * 16)) ^ swz;
          const f16x8 bh0 = *(const f16x8*)(smem + base0 + off);
          const f16x8 bh1 = *(const f16x8*)(smem + base1 + off);
          const f16x8 bl0 = *(const f16x8*)(smem + 16384 + base0 + off);
          const f16x8 bl1 = *(const f16x8*)(smem + 16384 + base1 + off);
          accG[0] = MFMA16(xa[0][ks], bh0, accG[0]);
          accG[1] = MFMA16(xa[1][ks], bh0, accG[1]);
          accG[2] = MFMA16(xa[0][ks], bh1, accG[2]);
          accG[3] = MFMA16(xa[1][ks], bh1, accG[3]);
          accG[4] = MFMA16(xa[0][ks], bl0, accG[4]);
          accG[5] = MFMA16(xa[1][ks], bl0, accG[5]);
          accG[6] = MFMA16(xa[0][ks], bl1, accG[6]);
          accG[7] = MFMA16(xa[1][ks], bl1, accG[7]);
        }
      } else {
#pragma unroll
        for (int ks = 0; ks < 8; ++ks) {
          const uint32_t off = ((uint32_t)(ks * 64 + lg * 16)) ^ swz;
          const f16x8 bh0 = *(const f16x8*)(smem + base0 + off);
          const f16x8 bh1 = *(const f16x8*)(smem + base1 + off);
          accG[0] = MFMA16(xa[0][ks], bh0, accG[0]);
          accG[1] = MFMA16(xa[1][ks], bh0, accG[1]);
          accG[2] = MFMA16(xa[0][ks], bh1, accG[2]);
          accG[3] = MFMA16(xa[1][ks], bh1, accG[3]);
        }
        // write accC = xl*W1h partial to LDS (f32, swizzled)
#pragma unroll
        for (int nt = 0; nt < 2; ++nt) {
#pragma unroll
          for (int mt = 0; mt < 2; ++mt) {
#pragma unroll
            for (int r = 0; r < 4; ++r) {
              const int row = wm * 32 + mt * 16 + lg * 4 + r;
              const int col = nt * 16 + l15;
              const uint32_t off = (uint32_t)(ACCOFF + row * 128) +
                                   (((uint32_t)(col * 4)) ^ ((row & 7) << 4));
              *(float*)(smem + off) = accG[nt * 2 + mt][r];
            }
          }
        }
      }
    }
    asm volatile("s_waitcnt lgkmcnt(0)" ::: "memory");
    __builtin_amdgcn_s_barrier();                       // barrier1: accC visible; W1 reads done
    __builtin_amdgcn_sched_barrier(0);

    if (t < NCHUNK - 1) stage_W1(smem, t + 1, w, lane); // 4 loads into freed W1 buf

    // ---- GELU(t) (wp==0): v = accA+accB+accC+b1 -> packed G ----
    if (wp == 0) {
      constexpr float C2 = -1.5957691216057308f;        // -2*sqrt(2/pi)
      constexpr float A2 = -0.071355071222456f;         // 0.044715*C2
#pragma unroll
      for (int nt = 0; nt < 2; ++nt) {
        const float bv = ((const float*)(smem + B1OFF))[t * 32 + nt * 16 + l15];
#pragma unroll
        for (int mt = 0; mt < 2; ++mt) {
#pragma unroll
          for (int r = 0; r < 4; ++r) {
            const int row = wm * 32 + mt * 16 + lg * 4 + r;
            const int col = nt * 16 + l15;
            const uint32_t soff = (((uint32_t)(col * 4)) ^ ((row & 7) << 4));
            const float c = *(const float*)(smem + ACCOFF + row * 128 + soff);
            const float v  = accG[nt * 2 + mt][r] + accG[4 + nt * 2 + mt][r] + c + bv;
            const float v2 = v * v;
            const float tE = v * __builtin_fmaf(v2, A2, C2);   // = -2u
            const float e  = __expf(tE);
            const float gv = __fdividef(v, 1.f + e);           // v*sigmoid(2u)
            const _Float16 gh = (_Float16)gv;
            const _Float16 gl = (_Float16)(gv - (float)gh);
            const uint32_t pk = (uint32_t)__builtin_bit_cast(unsigned short, gh) |
                                ((uint32_t)__builtin_bit_cast(unsigned short, gl) << 16);
            *(uint32_t*)(smem + GOFF + row * 128 + soff) = pk;
          }
        }
      }
    }
    asm volatile("s_waitcnt lgkmcnt(0)" ::: "memory");
    if (t == NCHUNK - 1) { asm volatile("s_waitcnt vmcnt(0)" ::: "memory"); }
    else                 { asm volatile("s_waitcnt vmcnt(4)" ::: "memory"); }
    __builtin_amdgcn_s_barrier();                       // barrier2: G visible; W2(t) certified
    __builtin_amdgcn_sched_barrier(0);

    // ---- GEMM2(t): acc2 += gh*W2h + gh*W2l + gl*W2h (all waves) ----
    {
      f16x8 ah[2], al[2];
#pragma unroll
      for (int mt = 0; mt < 2; ++mt) {
        const int row = wm * 32 + mt * 16 + l15;
        const uint32_t sw = (uint32_t)((row & 7) << 4);
        const uint32_t base = (uint32_t)(GOFF + row * 128);
        const u32x4 w0 = *(const u32x4*)(smem + base + (((uint32_t)(lg * 32)) ^ sw));
        const u32x4 w1v = *(const u32x4*)(smem + base + (((uint32_t)(lg * 32 + 16)) ^ sw));
        ah[mt] = unpack_half(w0, w1v, 0x05040100u);   // gh lanes
        al[mt] = unpack_half(w0, w1v, 0x07060302u);   // gl lanes
      }
#pragma unroll
      for (int nt = 0; nt < 8; ++nt) {
        const int n = wp * 128 + nt * 16 + l15;
        const uint32_t off = (uint32_t)(n * 64) +
                             (((uint32_t)(lg * 16)) ^ (((n >> 1) & 3) << 4));
        const f16x8 bh = *(const f16x8*)(smem + W2OFF + off);
        const f16x8 bl = *(const f16x8*)(smem + W2OFF + 16384 + off);
#pragma unroll
        for (int mt = 0; mt < 2; ++mt) {
          acc2[mt][nt] = MFMA16(ah[mt], bh, acc2[mt][nt]);
          acc2[mt][nt] = MFMA16(ah[mt], bl, acc2[mt][nt]);
          acc2[mt][nt] = MFMA16(al[mt], bh, acc2[mt][nt]);
        }
      }
    }
    asm volatile("s_waitcnt lgkmcnt(0)" ::: "memory");
    asm volatile("s_waitcnt vmcnt(0)" ::: "memory");
    __builtin_amdgcn_s_barrier();                       // barrier3: W2 free; W1(t+1) certified
    __builtin_amdgcn_sched_barrier(0);
  }
  __syncthreads();   // full drain before overlay

  // ---- epilogue: h = x + FFN + b2 (exact f32 residual), write h_hi ----
  {
    const float* xg = x + R * KDIM;
#pragma unroll
    for (int nt = 0; nt < 8; ++nt) {
      const float bv = b2[wp * 128 + nt * 16 + l15];
#pragma unroll
      for (int mt = 0; mt < 2; ++mt) {
#pragma unroll
        for (int r = 0; r < 4; ++r) {
          const int row = wm * 32 + mt * 16 + lg * 4 + r;
          const int col = wp * 128 + nt * 16 + l15;
          const float h = acc2[mt][nt][r] + xg[row * KDIM + col] + bv;
          acc2[mt][nt][r] = h;
          const uint32_t off = (uint32_t)(row * 512) +
                               (((uint32_t)(col * 2)) ^ ((row & 7) << 4));
          *(_Float16*)(smem + off) = (_Float16)h;
        }
      }
    }
  }
  __syncthreads();

  // ---- head GEMM pass 1+2: hh*Whh + hh*Whl ----
  f32x4 hacc = z4;
  const int hrow = wm * 32 + wp * 16 + l15;    // 8 disjoint 16-row slices
  const uint32_t hbase = hrow * 512;
  const uint32_t hswz  = (hrow & 7) << 4;
#pragma unroll
  for (int ks = 0; ks < 8; ++ks) {
    const uint32_t off = hbase + (((uint32_t)((ks * 32 + lg * 8) * 2)) ^ hswz);
    const f16x8 af  = *(const f16x8*)(smem + off);
    const f16x8 bhf = *(const f16x8*)(g_Whh + l15 * 256 + ks * 32 + lg * 8);
    const f16x8 blf = *(const f16x8*)(g_Whl + l15 * 256 + ks * 32 + lg * 8);
    hacc = MFMA16(af, bhf, hacc);
    hacc = MFMA16(af, blf, hacc);
  }
  __syncthreads();

  // ---- write h_lo over the same buffer ----
#pragma unroll
  for (int nt = 0; nt < 8; ++nt) {
#pragma unroll
    for (int mt = 0; mt < 2; ++mt) {
#pragma unroll
      for (int r = 0; r < 4; ++r) {
        const int row = wm * 32 + mt * 16 + lg * 4 + r;
        const int col = wp * 128 + nt * 16 + l15;
        const float h = acc2[mt][nt][r];
        const _Float16 hh = (_Float16)h;
        const uint32_t off = (uint32_t)(row * 512) +
                             (((uint32_t)(col * 2)) ^ ((row & 7) << 4));
        *(_Float16*)(smem + off) = (_Float16)(h - (float)hh);
      }
    }
  }
  __syncthreads();

  // ---- head pass 3: hl*Whh ----
#pragma unroll
  for (int ks = 0; ks < 8; ++ks) {
    const uint32_t off = hbase + (((uint32_t)((ks * 32 + lg * 8) * 2)) ^ hswz);
    const f16x8 af  = *(const f16x8*)(smem + off);
    const f16x8 bhf = *(const f16x8*)(g_Whh + l15 * 256 + ks * 32 + lg * 8);
    hacc = MFMA16(af, bhf, hacc);
  }
  const float hb = (l15 < 3) ? bval[l15] : ((l15 < 12) ? bvec[l15 - 3] : 0.f);
#pragma unroll
  for (int r = 0; r < 4; ++r) hacc[r] += hb;

  // ---- gather 12 head values per token, QR + cov ----
  float* hstg = (float*)(smem + 65536);   // disjoint from h buffer
#pragma unroll
  for (int r = 0; r < 4; ++r) {
    const int row = wm * 32 + wp * 16 + lg * 4 + r;
    hstg[row * 16 + l15] = hacc[r];
  }
  if (lane < 16) {
    const int row = wm * 32 + wp * 16 + lane;
    const float* hs = hstg + row * 16;
    float sp[3];
#pragma unroll
    for (int i = 0; i < 3; ++i) {
      const float s = hs[i];
      sp[i] = fmaxf(s, 0.f) + log1pf(__expf(-fabsf(s)));   // softplus
    }
    const float a0 = hs[3], a1 = hs[6], a2 = hs[9];
    const float b0 = hs[4], bc1 = hs[7], bc2 = hs[10];
    const float na = a0 * a0 + a1 * a1 + a2 * a2;
    const float ia = 1.f / sqrtf(fmaxf(na, 1e-30f));
    const float q00 = a0 * ia, q01 = a1 * ia, q02 = a2 * ia;
    const float d  = q00 * b0 + q01 * bc1 + q02 * bc2;
    const float u0 = b0 - d * q00, u1 = bc1 - d * q01, u2 = bc2 - d * q02;
    const float nu = u0 * u0 + u1 * u1 + u2 * u2;
    const float iu = 1.f / sqrtf(fmaxf(nu, 1e-30f));
    const float q10 = u0 * iu, q11 = u1 * iu, q12 = u2 * iu;
    const float q20 = q01 * q12 - q02 * q11;
    const float q21 = q02 * q10 - q00 * q12;
    const float q22 = q00 * q11 - q01 * q10;
    const float c00 = sp[0]*q00*q00 + sp[1]*q10*q10 + sp[2]*q20*q20 + 1e-8f;
    const float c11 = sp[0]*q01*q01 + sp[1]*q11*q11 + sp[2]*q21*q21 + 1e-8f;
    const float c22 = sp[0]*q02*q02 + sp[1]*q12*q12 + sp[2]*q22*q22 + 1e-8f;
    const float c01 = sp[0]*q00*q01 + sp[1]*q10*q11 + sp[2]*q20*q21;
    const float c02 = sp[0]*q00*q02 + sp[1]*q10*q12 + sp[2]*q20*q22;
    const float c12 = sp[0]*q01*q02 + sp[1]*q11*q12 + sp[2]*q21*q22;
    float* o = out + (size_t)(R + row) * 9;
    o[0] = c00; o[1] = c01; o[2] = c02;
    o[3] = c01; o[4] = c11; o[5] = c12;
    o[6] = c02; o[7] = c12; o[8] = c22;
  }
}

extern "C" void kernel_launch(void* const* d_in, const int* in_sizes, int n_in,
                              void* d_out, int out_size, void* d_ws, size_t ws_size,
                              hipStream_t stream) {
  const float* x    = (const float*)d_in[0];
  const float* W1   = (const float*)d_in[1];
  const float* b1   = (const float*)d_in[2];
  const float* W2   = (const float*)d_in[3];
  const float* b2   = (const float*)d_in[4];
  const float* Wval = (const float*)d_in[5];
  const float* bval = (const float*)d_in[6];
  const float* Wvec = (const float*)d_in[7];
  const float* bvec = (const float*)d_in[8];
  float* out = (float*)d_out;
  (void)in_sizes; (void)n_in; (void)out_size; (void)d_ws; (void)ws_size;

  hipFuncSetAttribute((const void*)fused_kernel,
                      hipFuncAttributeMaxDynamicSharedMemorySize, LDS_BYTES);

  prep_kernel<<<272, 256, 0, stream>>>(W1, W2, Wval, Wvec);
  fused_kernel<<<NBLOCKS, NTHREADS, LDS_BYTES, stream>>>(x, b1, b2, bval, bvec, out);
}

// Round 8
// 313.648 us; speedup vs baseline: 1.2248x; 1.0188x over previous
//
#include <hip/hip_runtime.h>
#include <cstdint>
#include <cstddef>

// ---------------- problem constants ----------------
#define TOKENS   65536      // B*N = 16*4096
#define KDIM     256        // model dim
#define HIDDEN   1024       // 4*dim
#define BM       64         // tokens per block (2 blocks/CU!)
#define HC       32         // hidden chunk width
#define NCHUNK   32         // HIDDEN / HC
#define NTHREADS 256        // 4 waves
#define NBLOCKS  (TOKENS / BM)

// LDS map (81920 B dynamic; 2 blocks x 80KB = 160KB = full CU pool):
//   steady state:
//     W1  @0      : 16K h | 16K l   (single buffer, restaged after barrier1)
//     W2  @32768  : 16K h | 16K l   (single buffer, restaged at loop top)
//     G   @65536  : 8K u32-packed (gh|gl<<16) [64][32]
//     accC@73728  : 4K f16 [64][32]  (xl*W1h partial; correction term -> f16 ok)
//     b1  @77824  : 4K f32[1024]
//   P0 overlay: x_hi @0..32K, x_lo @32K..64K (pre-loop only)
//   epilogue:  h fp16 [64][256] @0..32K ; hstg f32[64][16] @32768
#define W2OFF  32768
#define GOFF   65536
#define ACCOFF 73728
#define B1OFF  77824
#define LDS_BYTES 81920

using f16x8 = __attribute__((ext_vector_type(8))) _Float16;
using f16x4 = __attribute__((ext_vector_type(4))) _Float16;
using f32x4 = __attribute__((ext_vector_type(4))) float;
using u32x4 = __attribute__((ext_vector_type(4))) uint32_t;

// fp16 hi/lo split weights, pre-transposed + pre-swizzled per chunk so a
// LINEAR global_load_lds stage produces the swizzled LDS image directly.
// W1 plane: [c][n=32][k=256], byte = n*512 + ((g*16) ^ ((n&7)<<4))
// W2 plane: [c][n=256][k=32], byte = n*64  + ((g*16) ^ (((n>>1)&3)<<4))
__device__ __align__(16) _Float16 g_W1h[NCHUNK * HC * KDIM];
__device__ __align__(16) _Float16 g_W1l[NCHUNK * HC * KDIM];
__device__ __align__(16) _Float16 g_W2h[NCHUNK * KDIM * HC];
__device__ __align__(16) _Float16 g_W2l[NCHUNK * KDIM * HC];
__device__ __align__(16) _Float16 g_Whh[16 * KDIM];            // head rows j(16) x k(256)
__device__ __align__(16) _Float16 g_Whl[16 * KDIM];

// ---------------- prep: split + transpose + swizzle (dest-coalesced) ----------------
__global__ __launch_bounds__(256) void prep_kernel(
    const float* __restrict__ W1, const float* __restrict__ W2,
    const float* __restrict__ Wval, const float* __restrict__ Wvec) {
  const int tid = blockIdx.x * 256 + threadIdx.x;
  if (tid < 32768) {
    // W1: c(32) x n(32) x gd(32 dest k-octets)
    const int c = tid >> 10, n = (tid >> 5) & 31, gd = tid & 31;
    const int g = gd ^ (n & 7);          // swizzle is involutive on octet index
    const int hid = c * 32 + n;
    f16x8 hv, lv;
#pragma unroll
    for (int j = 0; j < 8; ++j) {
      const float wv = W1[(g * 8 + j) * HIDDEN + hid];
      const _Float16 hi = (_Float16)wv;
      hv[j] = hi;
      lv[j] = (_Float16)(wv - (float)hi);
    }
    const int dst = c * 8192 + n * 256 + gd * 8;
    *(f16x8*)(g_W1h + dst) = hv;
    *(f16x8*)(g_W1l + dst) = lv;
  } else if (tid < 65536) {
    // W2: c(32) x n(256) x gd(4)
    const int t = tid - 32768;
    const int c = t >> 10, n = (t >> 2) & 255, gd = t & 3;
    const int g = gd ^ ((n >> 1) & 3);
    f16x8 hv, lv;
#pragma unroll
    for (int j = 0; j < 8; ++j) {
      const float wv = W2[(c * 32 + g * 8 + j) * KDIM + n];
      const _Float16 hi = (_Float16)wv;
      hv[j] = hi;
      lv[j] = (_Float16)(wv - (float)hi);
    }
    const int dst = c * 8192 + n * 32 + gd * 8;
    *(f16x8*)(g_W2h + dst) = hv;
    *(f16x8*)(g_W2l + dst) = lv;
  } else if (tid < 65536 + 4096) {
    const int e = tid - 65536;
    const int j16 = e >> 8, k = e & 255;
    float wv = 0.f;
    if (j16 < 3) wv = Wval[k * 3 + j16];
    else if (j16 < 12) wv = Wvec[k * 9 + (j16 - 3)];
    const _Float16 hi = (_Float16)wv;
    g_Whh[e] = hi;
    g_Whl[e] = (_Float16)(wv - (float)hi);
  }
}

// stage one 32KB W-pair (h+l planes) into its SINGLE buffer:
// 4 waves x 8KB = EXACTLY 8 VMEM ops per wave (ledger-exact).
__device__ __forceinline__ void stage_W1(char* smem, int c, int w, int lane) {
  const char* base = (w < 2) ? (const char*)g_W1h : (const char*)g_W1l;
  const char* s = base + (size_t)c * 16384 + (size_t)(w & 1) * 8192 + (size_t)lane * 16;
  char* d = smem + ((w < 2) ? 0 : 16384) + (w & 1) * 8192;
#pragma unroll
  for (int i = 0; i < 8; ++i) {
    __builtin_amdgcn_global_load_lds(
        (__attribute__((address_space(1))) void*)(void*)(s + i * 1024),
        (__attribute__((address_space(3))) void*)(d + i * 1024), 16, 0, 0);
  }
}
__device__ __forceinline__ void stage_W2(char* smem, int c, int w, int lane) {
  const char* base = (w < 2) ? (const char*)g_W2h : (const char*)g_W2l;
  const char* s = base + (size_t)c * 16384 + (size_t)(w & 1) * 8192 + (size_t)lane * 16;
  char* d = smem + W2OFF + ((w < 2) ? 0 : 16384) + (w & 1) * 8192;
#pragma unroll
  for (int i = 0; i < 8; ++i) {
    __builtin_amdgcn_global_load_lds(
        (__attribute__((address_space(1))) void*)(void*)(s + i * 1024),
        (__attribute__((address_space(3))) void*)(d + i * 1024), 16, 0, 0);
  }
}

__device__ __forceinline__ f16x8 unpack_half(const u32x4 a, const u32x4 b, uint32_t sel) {
  u32x4 r;
  r[0] = __builtin_amdgcn_perm(a[1], a[0], sel);
  r[1] = __builtin_amdgcn_perm(a[3], a[2], sel);
  r[2] = __builtin_amdgcn_perm(b[1], b[0], sel);
  r[3] = __builtin_amdgcn_perm(b[3], b[2], sel);
  return __builtin_bit_cast(f16x8, r);
}

#define MFMA16(a, b, c) __builtin_amdgcn_mfma_f32_16x16x32_f16((a), (b), (c), 0, 0, 0)

// ---------------- fused FFN + heads + QR/cov ----------------
// 4 waves: wm = w&1 owns token rows [32wm,32wm+32); wp = w>>1.
//   wp==0: holds x_hi frags; GEMM1 passes xh*W1h, xh*W1l; does GELU.
//   wp==1: holds x_lo frags; GEMM1 pass  xl*W1h -> accC (f16) via LDS.
// GEMM2: all 4 waves, col half = wp*128.
//
// Per-iter sync (R7-verified, cross-wave-safe):
//   top: stage_W2(t) [8 loads]
//   GEMM1 (+accC write)            -> lgkm(0); barrier1
//   if t<31 stage_W1(t+1) [8 loads]
//   GELU (wp==0): accA+accB+accC+b1 -> G
//                                  -> lgkm(0); vmcnt(8 | 0@t=31); barrier2
//        (certifies W2(t): 8 newer W1 loads stay in flight)
//   GEMM2 reads G + W2(t)          -> lgkm(0); vmcnt(0); barrier3
__global__ __launch_bounds__(NTHREADS, 2) void fused_kernel(
    const float* __restrict__ x, const float* __restrict__ b1,
    const float* __restrict__ b2, const float* __restrict__ bval,
    const float* __restrict__ bvec, float* __restrict__ out) {
  extern __shared__ char smem[];
  const int tid  = threadIdx.x;
  const int lane = tid & 63;
  const int w    = tid >> 6;     // wave 0..3
  const int wm   = w & 1;        // row group (32 rows)
  const int wp   = w >> 1;       // plane/role (GEMM1), col half (GEMM2)
  const int l15  = lane & 15;
  const int lg   = lane >> 4;
  const int64_t R = (int64_t)blockIdx.x * BM;

  // ---- P0: stage x tile as fp16 hi/lo (row-swizzled) ----
  {
    const float* xg = x + R * KDIM;
#pragma unroll
    for (int i = 0; i < 16; ++i) {
      const int fidx = tid + NTHREADS * i;      // 4096 float4s total
      const int row  = fidx >> 6;               // 0..63
      const int f4   = fidx & 63;
      const float4 v = *(const float4*)(xg + row * KDIM + f4 * 4);
      const _Float16 h0 = (_Float16)v.x, h1 = (_Float16)v.y,
                     h2 = (_Float16)v.z, h3 = (_Float16)v.w;
      f16x4 hv = {h0, h1, h2, h3};
      f16x4 lv = {(_Float16)(v.x - (float)h0), (_Float16)(v.y - (float)h1),
                  (_Float16)(v.z - (float)h2), (_Float16)(v.w - (float)h3)};
      const uint32_t off = (uint32_t)(row * 512) +
                           (((uint32_t)(f4 * 8)) ^ ((row & 7) << 4));
      *(f16x4*)(smem + off)         = hv;
      *(f16x4*)(smem + 32768 + off) = lv;
    }
  }
  __syncthreads();

  // ---- P1: per-wave x A-fragments, ONE plane (wp) only: 64 VGPR ----
  f16x8 xa[2][8];
  {
    const char* xplane = smem + wp * 32768;
#pragma unroll
    for (int mt = 0; mt < 2; ++mt) {
      const int row = wm * 32 + mt * 16 + l15;
      const uint32_t rbase = row * 512;
      const uint32_t swz = (row & 7) << 4;
#pragma unroll
      for (int ks = 0; ks < 8; ++ks) {
        const uint32_t off = rbase + (((uint32_t)((ks * 32 + lg * 8) * 2)) ^ swz);
        xa[mt][ks] = *(const f16x8*)(xplane + off);
      }
    }
  }
  __syncthreads();   // x reads drained; overlay area free

  // ---- prologue: b1 -> LDS, stage W1(0); full drain before loop ----
  {
    float* b1l = (float*)(smem + B1OFF);
#pragma unroll
    for (int i = 0; i < 4; ++i) b1l[tid + 256 * i] = b1[tid + 256 * i];
  }
  stage_W1(smem, 0, w, lane);
  __syncthreads();   // full vmcnt/lgkm drain: W1(0)+b1 in LDS for all waves

  const f32x4 z4 = {0.f, 0.f, 0.f, 0.f};
  f32x4 acc2[2][8];
#pragma unroll
  for (int mt = 0; mt < 2; ++mt)
#pragma unroll
    for (int nt = 0; nt < 8; ++nt) acc2[mt][nt] = z4;

  // ---- chunk loop: 3-barrier lockstep, single-buffered weights ----
#pragma unroll 1
  for (int t = 0; t < NCHUNK; ++t) {
    stage_W2(smem, t, w, lane);            // 8 loads; certified at barrier2

    // ---- GEMM1(t): plane-split ----
    // accG[0..3] = {A (wp0) or C (wp1)}[nt*2+mt]; accG[4..7] = B[nt*2+mt] (wp0)
    f32x4 accG[8] = {z4, z4, z4, z4, z4, z4, z4, z4};
    {
      const uint32_t swz   = (uint32_t)((l15 & 7) << 4);
      const uint32_t base0 = (uint32_t)(l15 * 512);
      const uint32_t base1 = (uint32_t)((16 + l15) * 512);
      if (wp == 0) {
#pragma unroll
        for (int ks = 0; ks < 8; ++ks) {
          const uint32_t off = ((uint32_t)(ks * 64 + lg * 16)) ^ swz;
          const f16x8 bh0 = *(const f16x8*)(smem + base0 + off);
          const f16x8 bh1 = *(const f16x8*)(smem + base1 + off);
          const f16x8 bl0 = *(const f16x8*)(smem + 16384 + base0 + off);
          const f16x8 bl1 = *(const f16x8*)(smem + 16384 + base1 + off);
          accG[0] = MFMA16(xa[0][ks], bh0, accG[0]);
          accG[1] = MFMA16(xa[1][ks], bh0, accG[1]);
          accG[2] = MFMA16(xa[0][ks], bh1, accG[2]);
          accG[3] = MFMA16(xa[1][ks], bh1, accG[3]);
          accG[4] = MFMA16(xa[0][ks], bl0, accG[4]);
          accG[5] = MFMA16(xa[1][ks], bl0, accG[5]);
          accG[6] = MFMA16(xa[0][ks], bl1, accG[6]);
          accG[7] = MFMA16(xa[1][ks], bl1, accG[7]);
        }
      } else {
#pragma unroll
        for (int ks = 0; ks < 8; ++ks) {
          const uint32_t off = ((uint32_t)(ks * 64 + lg * 16)) ^ swz;
          const f16x8 bh0 = *(const f16x8*)(smem + base0 + off);
          const f16x8 bh1 = *(const f16x8*)(smem + base1 + off);
          accG[0] = MFMA16(xa[0][ks], bh0, accG[0]);
          accG[1] = MFMA16(xa[1][ks], bh0, accG[1]);
          accG[2] = MFMA16(xa[0][ks], bh1, accG[2]);
          accG[3] = MFMA16(xa[1][ks], bh1, accG[3]);
        }
        // write accC = xl*W1h partial to LDS as f16 (correction term)
#pragma unroll
        for (int nt = 0; nt < 2; ++nt) {
#pragma unroll
          for (int mt = 0; mt < 2; ++mt) {
#pragma unroll
            for (int r = 0; r < 4; ++r) {
              const int row = wm * 32 + mt * 16 + lg * 4 + r;
              const int col = nt * 16 + l15;
              const uint32_t off = (uint32_t)(ACCOFF + row * 64) +
                                   (((uint32_t)(col * 2)) ^ ((row & 3) << 4));
              *(_Float16*)(smem + off) = (_Float16)accG[nt * 2 + mt][r];
            }
          }
        }
      }
    }
    asm volatile("s_waitcnt lgkmcnt(0)" ::: "memory");
    __builtin_amdgcn_s_barrier();                       // barrier1: accC visible; W1 reads done
    __builtin_amdgcn_sched_barrier(0);

    if (t < NCHUNK - 1) stage_W1(smem, t + 1, w, lane); // 8 loads into freed W1 buf

    // ---- GELU(t) (wp==0): v = accA+accB+accC+b1 -> packed G ----
    if (wp == 0) {
      constexpr float C2 = -1.5957691216057308f;        // -2*sqrt(2/pi)
      constexpr float A2 = -0.071355071222456f;         // 0.044715*C2
#pragma unroll
      for (int nt = 0; nt < 2; ++nt) {
        const float bv = ((const float*)(smem + B1OFF))[t * 32 + nt * 16 + l15];
#pragma unroll
        for (int mt = 0; mt < 2; ++mt) {
#pragma unroll
          for (int r = 0; r < 4; ++r) {
            const int row = wm * 32 + mt * 16 + lg * 4 + r;
            const int col = nt * 16 + l15;
            const uint32_t coff = (uint32_t)(ACCOFF + row * 64) +
                                  (((uint32_t)(col * 2)) ^ ((row & 3) << 4));
            const float c = (float)(*(const _Float16*)(smem + coff));
            const float v  = accG[nt * 2 + mt][r] + accG[4 + nt * 2 + mt][r] + c + bv;
            const float v2 = v * v;
            const float tE = v * __builtin_fmaf(v2, A2, C2);   // = -2u
            const float e  = __expf(tE);
            const float gv = __fdividef(v, 1.f + e);           // v*sigmoid(2u)
            const _Float16 gh = (_Float16)gv;
            const _Float16 gl = (_Float16)(gv - (float)gh);
            const uint32_t pk = (uint32_t)__builtin_bit_cast(unsigned short, gh) |
                                ((uint32_t)__builtin_bit_cast(unsigned short, gl) << 16);
            const uint32_t goff = (uint32_t)(GOFF + row * 128) +
                                  (((uint32_t)(col * 4)) ^ ((row & 7) << 4));
            *(uint32_t*)(smem + goff) = pk;
          }
        }
      }
    }
    asm volatile("s_waitcnt lgkmcnt(0)" ::: "memory");
    if (t == NCHUNK - 1) { asm volatile("s_waitcnt vmcnt(0)" ::: "memory"); }
    else                 { asm volatile("s_waitcnt vmcnt(8)" ::: "memory"); }
    __builtin_amdgcn_s_barrier();                       // barrier2: G visible; W2(t) certified
    __builtin_amdgcn_sched_barrier(0);

    // ---- GEMM2(t): acc2 += gh*W2h + gh*W2l + gl*W2h (all waves) ----
    {
      f16x8 ah[2], al[2];
#pragma unroll
      for (int mt = 0; mt < 2; ++mt) {
        const int row = wm * 32 + mt * 16 + l15;
        const uint32_t sw = (uint32_t)((row & 7) << 4);
        const uint32_t base = (uint32_t)(GOFF + row * 128);
        const u32x4 w0 = *(const u32x4*)(smem + base + (((uint32_t)(lg * 32)) ^ sw));
        const u32x4 w1v = *(const u32x4*)(smem + base + (((uint32_t)(lg * 32 + 16)) ^ sw));
        ah[mt] = unpack_half(w0, w1v, 0x05040100u);   // gh lanes
        al[mt] = unpack_half(w0, w1v, 0x07060302u);   // gl lanes
      }
#pragma unroll
      for (int nt = 0; nt < 8; ++nt) {
        const int n = wp * 128 + nt * 16 + l15;
        const uint32_t off = (uint32_t)(n * 64) +
                             (((uint32_t)(lg * 16)) ^ (((n >> 1) & 3) << 4));
        const f16x8 bh = *(const f16x8*)(smem + W2OFF + off);
        const f16x8 bl = *(const f16x8*)(smem + W2OFF + 16384 + off);
#pragma unroll
        for (int mt = 0; mt < 2; ++mt) {
          acc2[mt][nt] = MFMA16(ah[mt], bh, acc2[mt][nt]);
          acc2[mt][nt] = MFMA16(ah[mt], bl, acc2[mt][nt]);
          acc2[mt][nt] = MFMA16(al[mt], bh, acc2[mt][nt]);
        }
      }
    }
    asm volatile("s_waitcnt lgkmcnt(0)" ::: "memory");
    asm volatile("s_waitcnt vmcnt(0)" ::: "memory");
    __builtin_amdgcn_s_barrier();                       // barrier3: W2 free; W1(t+1) certified
    __builtin_amdgcn_sched_barrier(0);
  }
  __syncthreads();   // full drain before overlay

  // ---- epilogue: h = x + FFN + b2 (exact f32 residual), write h_hi ----
  {
    const float* xg = x + R * KDIM;
#pragma unroll
    for (int nt = 0; nt < 8; ++nt) {
      const float bv = b2[wp * 128 + nt * 16 + l15];
#pragma unroll
      for (int mt = 0; mt < 2; ++mt) {
#pragma unroll
        for (int r = 0; r < 4; ++r) {
          const int row = wm * 32 + mt * 16 + lg * 4 + r;
          const int col = wp * 128 + nt * 16 + l15;
          const float h = acc2[mt][nt][r] + xg[row * KDIM + col] + bv;
          acc2[mt][nt][r] = h;
          const uint32_t off = (uint32_t)(row * 512) +
                               (((uint32_t)(col * 2)) ^ ((row & 7) << 4));
          *(_Float16*)(smem + off) = (_Float16)h;
        }
      }
    }
  }
  __syncthreads();

  // ---- head GEMM pass 1+2: hh*Whh + hh*Whl ----
  f32x4 hacc = z4;
  const int hrow = wm * 32 + wp * 16 + l15;    // 4 disjoint 16-row slices
  const uint32_t hbase = hrow * 512;
  const uint32_t hswz  = (hrow & 7) << 4;
#pragma unroll
  for (int ks = 0; ks < 8; ++ks) {
    const uint32_t off = hbase + (((uint32_t)((ks * 32 + lg * 8) * 2)) ^ hswz);
    const f16x8 af  = *(const f16x8*)(smem + off);
    const f16x8 bhf = *(const f16x8*)(g_Whh + l15 * 256 + ks * 32 + lg * 8);
    const f16x8 blf = *(const f16x8*)(g_Whl + l15 * 256 + ks * 32 + lg * 8);
    hacc = MFMA16(af, bhf, hacc);
    hacc = MFMA16(af, blf, hacc);
  }
  __syncthreads();

  // ---- write h_lo over the same buffer ----
#pragma unroll
  for (int nt = 0; nt < 8; ++nt) {
#pragma unroll
    for (int mt = 0; mt < 2; ++mt) {
#pragma unroll
      for (int r = 0; r < 4; ++r) {
        const int row = wm * 32 + mt * 16 + lg * 4 + r;
        const int col = wp * 128 + nt * 16 + l15;
        const float h = acc2[mt][nt][r];
        const _Float16 hh = (_Float16)h;
        const uint32_t off = (uint32_t)(row * 512) +
                             (((uint32_t)(col * 2)) ^ ((row & 7) << 4));
        *(_Float16*)(smem + off) = (_Float16)(h - (float)hh);
      }
    }
  }
  __syncthreads();

  // ---- head pass 3: hl*Whh ----
#pragma unroll
  for (int ks = 0; ks < 8; ++ks) {
    const uint32_t off = hbase + (((uint32_t)((ks * 32 + lg * 8) * 2)) ^ hswz);
    const f16x8 af  = *(const f16x8*)(smem + off);
    const f16x8 bhf = *(const f16x8*)(g_Whh + l15 * 256 + ks * 32 + lg * 8);
    hacc = MFMA16(af, bhf, hacc);
  }
  const float hb = (l15 < 3) ? bval[l15] : ((l15 < 12) ? bvec[l15 - 3] : 0.f);
#pragma unroll
  for (int r = 0; r < 4; ++r) hacc[r] += hb;

  // ---- gather 12 head values per token, QR + cov ----
  float* hstg = (float*)(smem + 32768);   // disjoint from h buffer (0..32K)
#pragma unroll
  for (int r = 0; r < 4; ++r) {
    const int row = wm * 32 + wp * 16 + lg * 4 + r;
    hstg[row * 16 + l15] = hacc[r];
  }
  if (lane < 16) {
    const int row = wm * 32 + wp * 16 + lane;
    const float* hs = hstg + row * 16;
    float sp[3];
#pragma unroll
    for (int i = 0; i < 3; ++i) {
      const float s = hs[i];
      sp[i] = fmaxf(s, 0.f) + log1pf(__expf(-fabsf(s)));   // softplus
    }
    const float a0 = hs[3], a1 = hs[6], a2 = hs[9];
    const float b0 = hs[4], bc1 = hs[7], bc2 = hs[10];
    const float na = a0 * a0 + a1 * a1 + a2 * a2;
    const float ia = 1.f / sqrtf(fmaxf(na, 1e-30f));
    const float q00 = a0 * ia, q01 = a1 * ia, q02 = a2 * ia;
    const float d  = q00 * b0 + q01 * bc1 + q02 * bc2;
    const float u0 = b0 - d * q00, u1 = bc1 - d * q01, u2 = bc2 - d * q02;
    const float nu = u0 * u0 + u1 * u1 + u2 * u2;
    const float iu = 1.f / sqrtf(fmaxf(nu, 1e-30f));
    const float q10 = u0 * iu, q11 = u1 * iu, q12 = u2 * iu;
    const float q20 = q01 * q12 - q02 * q11;
    const float q21 = q02 * q10 - q00 * q12;
    const float q22 = q00 * q11 - q01 * q10;
    const float c00 = sp[0]*q00*q00 + sp[1]*q10*q10 + sp[2]*q20*q20 + 1e-8f;
    const float c11 = sp[0]*q01*q01 + sp[1]*q11*q11 + sp[2]*q21*q21 + 1e-8f;
    const float c22 = sp[0]*q02*q02 + sp[1]*q12*q12 + sp[2]*q22*q22 + 1e-8f;
    const float c01 = sp[0]*q00*q01 + sp[1]*q10*q11 + sp[2]*q20*q21;
    const float c02 = sp[0]*q00*q02 + sp[1]*q10*q12 + sp[2]*q20*q22;
    const float c12 = sp[0]*q01*q02 + sp[1]*q11*q12 + sp[2]*q21*q22;
    float* o = out + (size_t)(R + row) * 9;
    o[0] = c00; o[1] = c01; o[2] = c02;
    o[3] = c01; o[4] = c11; o[5] = c12;
    o[6] = c02; o[7] = c12; o[8] = c22;
  }
}

extern "C" void kernel_launch(void* const* d_in, const int* in_sizes, int n_in,
                              void* d_out, int out_size, void* d_ws, size_t ws_size,
                              hipStream_t stream) {
  const float* x    = (const float*)d_in[0];
  const float* W1   = (const float*)d_in[1];
  const float* b1   = (const float*)d_in[2];
  const float* W2   = (const float*)d_in[3];
  const float* b2   = (const float*)d_in[4];
  const float* Wval = (const float*)d_in[5];
  const float* bval = (const float*)d_in[6];
  const float* Wvec = (const float*)d_in[7];
  const float* bvec = (const float*)d_in[8];
  float* out = (float*)d_out;
  (void)in_sizes; (void)n_in; (void)out_size; (void)d_ws; (void)ws_size;

  hipFuncSetAttribute((const void*)fused_kernel,
                      hipFuncAttributeMaxDynamicSharedMemorySize, LDS_BYTES);

  prep_kernel<<<272, 256, 0, stream>>>(W1, W2, Wval, Wvec);
  fused_kernel<<<NBLOCKS, NTHREADS, LDS_BYTES, stream>>>(x, b1, b2, bval, bvec, out);
}